// Round 16
// baseline (371.620 us; speedup 1.0000x reference)
//
#include <hip/hip_runtime.h>

// WaveletFeatureExtractor: db4 wavedec (5 levels, symmetric pad) -> adaptive pool 128
// -> per-level 128x128 MLP (ReLU) -> fused 640->512 MLP (ReLU).
//
// Round 16: staged-w banded kernel. r14/r15 showed hipcc won't pipeline
// scattered per-lane L2 loads (VALUBusy 13-16%, latency-bound) but it streams
// bulk copies fine. So: 20 passes x 32 outputs; each pass's 32 w-rows are a
// CONTIGUOUS 32KB chunk -> T14 async split (load next pass's chunk to regs
// before computing current pass from LDS; write after barrier). Dot = pure LDS,
// 4 granules/lane (16 lanes/output), WLEN=512. meta load removed: sx computed
// analytically (same ws=max(2ws-6,0) recursion as build_w).
// build_w (adjoint, verified r13) -> wt[640][512] f16. r10-cascade fallback.

#define BATCH   2048
#define SIGLEN  16384
#define N1      8195
#define N2      4101
#define N3      2054
#define N4      1030
#define N5      518
#define POOLP   128
#define COMB    640
#define OUTD    512
#define WLEN    512   // 64 granules of 8 f16; true window <= 388

typedef __fp16 h2 __attribute__((ext_vector_type(2)));

__device__ constexpr float LO[8] = {
     0.2303778133088965f,   0.7148465705529157f,   0.6308807679298589f,
    -0.027983769416859854f, -0.18703481171909309f,  0.030841381835560764f,
     0.0328830116668852f,  -0.010597401785069032f };
__device__ constexpr float HI[8] = {
    -0.010597401785069032f, -0.0328830116668852f,   0.030841381835560764f,
     0.18703481171909309f,  -0.027983769416859854f, -0.6308807679298589f,
     0.7148465705529157f,  -0.2303778133088965f };

// ---------------- build_w: adjoint cascade -> banded rows (verified r13) ------
__global__ __launch_bounds__(128) void build_w(h2* __restrict__ wt)  // [640][WLEN/2]
{
    __shared__ float g0[512], g1[512];
    const int c = blockIdx.x;
    const int slot = c >> 7, p = c & 127;
    const int tid = threadIdx.x;

    const int bandN[5] = {N5, N5, N4, N3, N2};
    const int M = bandN[slot];
    const int s = (p * M) >> 7;
    const int e = ((p + 1) * M + 127) >> 7;

    for (int i = tid; i < 512; i += 128) { g0[i] = 0.f; g1[i] = 0.f; }
    __syncthreads();
    const float inv = 1.f / (float)(e - s);
    for (int i = tid; i < e - s; i += 128) g0[i] = inv;
    __syncthreads();

    float* cur = g0;
    float* nxt = g1;
    int ws = s, we = e;

    const int nsteps = (slot <= 1) ? 5 : (6 - slot);     // 5,5,4,3,2
    const int nins[5] = {N4, N3, N2, N1, SIGLEN};
    const int start = 5 - nsteps;

    for (int st = 0; st < nsteps; ++st) {
        const int Nin = nins[start + st];
        const bool useHI = (st == 0 && slot >= 1);
        const int nws = (2 * ws - 6 < 0) ? 0 : (2 * ws - 6);
        const int nwe = (2 * we < Nin) ? (2 * we) : Nin;
        for (int i = tid; i < nwe - nws; i += 128) nxt[i] = 0.f;
        __syncthreads();
        for (int t = 0; t < 8; ++t) {
            const float f = useHI ? HI[t] : LO[t];
            for (int j = ws + tid; j < we; j += 128) {
                int idx = 2 * j - 6 + t;
                idx = (idx < 0) ? (-1 - idx) : idx;
                idx = (idx >= Nin) ? (2 * Nin - 1 - idx) : idx;
                nxt[idx - nws] += f * cur[j - ws];
            }
            __syncthreads();
        }
        float* tmp = cur; cur = nxt; nxt = tmp;
        ws = nws; we = nwe;
    }

    const int sx0 = ws & ~7;                 // 8-elem aligned; kernel recomputes this
    __fp16* wrow = reinterpret_cast<__fp16*>(wt + (size_t)c * (WLEN / 2));
    for (int i = tid; i < WLEN; i += 128) {
        const int idx = sx0 + i;
        const float v = (idx >= ws && idx < we) ? cur[idx - ws] : 0.f;
        wrow[i] = (__fp16)v;
    }
}

// ---------- staged-w banded dot: 20 passes x 32 outputs, pure-LDS dot ----
__global__ __launch_bounds__(512) void banded_kernel(const float* __restrict__ x,
                                                     const h2* __restrict__ wt,
                                                     float* __restrict__ pooled) {
    __shared__ __align__(16) unsigned int xs_u[SIGLEN / 2 + 256]; // f16 pairs + 1KB zero pad
    __shared__ __align__(16) float wtile[32 * (WLEN / 2)];        // 32 rows x 512 f16 = 32KB

    const int tid = threadIdx.x;
    const int row = blockIdx.x;
    const float* __restrict__ xr = x + (size_t)row * SIGLEN;

    // stage x -> f16 pairs
    for (int i = tid; i < SIGLEN / 4; i += 512) {
        const float4 v = *reinterpret_cast<const float4*>(xr + 4 * i);
        const h2 p0 = __builtin_amdgcn_cvt_pkrtz(v.x, v.y);
        const h2 p1 = __builtin_amdgcn_cvt_pkrtz(v.z, v.w);
        uint2 pk;
        pk.x = __builtin_bit_cast(unsigned int, p0);
        pk.y = __builtin_bit_cast(unsigned int, p1);
        *reinterpret_cast<uint2*>(xs_u + 2 * i) = pk;
    }
    if (tid < 256) xs_u[SIGLEN / 2 + tid] = 0u;

    // stage wtile for pass 0 (contiguous 32KB chunk)
    {
        const float4* src = reinterpret_cast<const float4*>(wt);
        float4* dst = reinterpret_cast<float4*>(wtile);
#pragma unroll
        for (int k = 0; k < 4; ++k) dst[tid + 512 * k] = src[tid + 512 * k];
    }
    __syncthreads();

    const float* __restrict__ xs_f = reinterpret_cast<const float*>(xs_u);
    const int sub = tid & 15;
    const int cb  = tid >> 4;                 // 0..31

    for (int pass = 0; pass < 20; ++pass) {
        // T14 async split: issue next chunk's loads BEFORE computing this pass
        float4 st[4];
        const bool more = (pass < 19);
        if (more) {
            const float4* nsrc = reinterpret_cast<const float4*>(wt + (size_t)(pass + 1) * 8192);
#pragma unroll
            for (int k = 0; k < 4; ++k) st[k] = nsrc[tid + 512 * k];
        }

        // compute 32 outputs from LDS (analytic sx: same recursion as build_w)
        const int c = pass * 32 + cb;
        const int slot = c >> 7, p = c & 127;
        const int M = (slot <= 1) ? N5 : (slot == 2 ? N4 : (slot == 3 ? N3 : N2));
        const int nst = (slot <= 1) ? 5 : (6 - slot);
        int ws = (p * M) >> 7;
#pragma unroll
        for (int k = 0; k < 5; ++k) {
            if (k < nst) { int t = 2 * ws - 6; ws = (t < 0) ? 0 : t; }
        }
        const int sxh = (ws & ~7) >> 1;       // float-index, 16B-aligned

        float acc = 0.f;
        const float* wrow_f = wtile + cb * (WLEN / 2);
#pragma unroll
        for (int i = 0; i < 4; ++i) {
            const int g = sub + 16 * i;
            const float4 xv = *reinterpret_cast<const float4*>(xs_f + sxh + 4 * g);
            const float4 wv = *reinterpret_cast<const float4*>(wrow_f + 4 * g);
            acc = __builtin_amdgcn_fdot2(__builtin_bit_cast(h2, xv.x), __builtin_bit_cast(h2, wv.x), acc, false);
            acc = __builtin_amdgcn_fdot2(__builtin_bit_cast(h2, xv.y), __builtin_bit_cast(h2, wv.y), acc, false);
            acc = __builtin_amdgcn_fdot2(__builtin_bit_cast(h2, xv.z), __builtin_bit_cast(h2, wv.z), acc, false);
            acc = __builtin_amdgcn_fdot2(__builtin_bit_cast(h2, xv.w), __builtin_bit_cast(h2, wv.w), acc, false);
        }
        acc += __shfl_xor(acc, 1);
        acc += __shfl_xor(acc, 2);
        acc += __shfl_xor(acc, 4);
        acc += __shfl_xor(acc, 8);
        if (sub == 0) pooled[(size_t)row * COMB + c] = acc;

        __syncthreads();                      // all reads of wtile done
        if (more) {
            float4* dst = reinterpret_cast<float4*>(wtile);
#pragma unroll
            for (int k = 0; k < 4; ++k) dst[tid + 512 * k] = st[k];
        }
        __syncthreads();                      // new wtile visible
    }
}

// ---------------- Fallback dwt cascade (round 10, proven) ----------------

#define SWZ(i) ((i) ^ ((((i) >> 5) & 7) << 2))
#define NTHR 512

__device__ __forceinline__ int symfold(int idx, int n) {
    idx = (idx < 0) ? (-1 - idx) : idx;
    idx = (idx >= n) ? (2 * n - 1 - idx) : idx;
    return idx;
}
constexpr int cmin(int a, int b) { return a < b ? a : b; }
constexpr int cmax(int a, int b) { return a > b ? a : b; }

template<int SS, int SE, int BSRC, int NSRC, int S, int E, int BDST>
__device__ __forceinline__ void dwt_chunk(const float* __restrict__ src,
                                          float* __restrict__ dstA,
                                          float* __restrict__ dstD, int tid) {
    for (int j0 = (S & ~3) + tid * 4; j0 < E; j0 += NTHR * 4) {
        const int rb = 2 * j0 - 8;
        if ((rb >= SS) && (2 * j0 + 7 <= SE - 1) && (j0 + 4 <= E)) {
            const int lrb = rb - BSRC;
            const float4 v0 = *reinterpret_cast<const float4*>(src + SWZ(lrb));
            const float4 v1 = *reinterpret_cast<const float4*>(src + SWZ(lrb + 4));
            const float4 v2 = *reinterpret_cast<const float4*>(src + SWZ(lrb + 8));
            const float4 v3 = *reinterpret_cast<const float4*>(src + SWZ(lrb + 12));
            float w[16];
            w[0]=v0.x;  w[1]=v0.y;  w[2]=v0.z;  w[3]=v0.w;
            w[4]=v1.x;  w[5]=v1.y;  w[6]=v1.z;  w[7]=v1.w;
            w[8]=v2.x;  w[9]=v2.y;  w[10]=v2.z; w[11]=v2.w;
            w[12]=v3.x; w[13]=v3.y; w[14]=v3.z; w[15]=v3.w;
            float a[4], d[4];
#pragma unroll
            for (int k = 0; k < 4; ++k) {
                float aa = 0.f, dd = 0.f;
#pragma unroll
                for (int t = 0; t < 8; ++t) {
                    const float v = w[2 + 2 * k + t];
                    aa = fmaf(v, LO[t], aa);
                    dd = fmaf(v, HI[t], dd);
                }
                a[k] = aa; d[k] = dd;
            }
            const int ds = j0 - BDST;
            *reinterpret_cast<float4*>(dstA + SWZ(ds)) = make_float4(a[0], a[1], a[2], a[3]);
            *reinterpret_cast<float4*>(dstD + SWZ(ds)) = make_float4(d[0], d[1], d[2], d[3]);
        } else {
            for (int k = 0; k < 4; ++k) {
                const int j = j0 + k;
                if (j < S || j >= E) continue;
                float aa = 0.f, dd = 0.f;
#pragma unroll
                for (int t = 0; t < 8; ++t) {
                    const int idx = symfold(2 * j - 6 + t, NSRC);
                    const float v = src[SWZ(idx - BSRC)];
                    aa = fmaf(v, LO[t], aa);
                    dd = fmaf(v, HI[t], dd);
                }
                dstA[SWZ(j - BDST)] = aa;
                dstD[SWZ(j - BDST)] = dd;
            }
        }
    }
}

template<int S, int E, int BDST>
__device__ __forceinline__ void dwt_l1(const float* __restrict__ xr,
                                       float* __restrict__ dstA, int tid) {
    for (int j0 = (S & ~3) + tid * 4; j0 < E; j0 += NTHR * 4) {
        const int rb = 2 * j0 - 8;
        if ((rb >= 0) && (2 * j0 + 7 <= SIGLEN - 1) && (j0 + 4 <= E)) {
            const float4* s4 = reinterpret_cast<const float4*>(xr + rb);
            const float4 v0 = s4[0], v1 = s4[1], v2 = s4[2], v3 = s4[3];
            float w[16];
            w[0]=v0.x;  w[1]=v0.y;  w[2]=v0.z;  w[3]=v0.w;
            w[4]=v1.x;  w[5]=v1.y;  w[6]=v1.z;  w[7]=v1.w;
            w[8]=v2.x;  w[9]=v2.y;  w[10]=v2.z; w[11]=v2.w;
            w[12]=v3.x; w[13]=v3.y; w[14]=v3.z; w[15]=v3.w;
            float a[4];
#pragma unroll
            for (int k = 0; k < 4; ++k) {
                float aa = 0.f;
#pragma unroll
                for (int t = 0; t < 8; ++t) aa = fmaf(w[2 + 2 * k + t], LO[t], aa);
                a[k] = aa;
            }
            *reinterpret_cast<float4*>(dstA + SWZ(j0 - BDST)) = make_float4(a[0], a[1], a[2], a[3]);
        } else {
            for (int k = 0; k < 4; ++k) {
                const int j = j0 + k;
                if (j < S || j >= E) continue;
                float aa = 0.f;
#pragma unroll
                for (int t = 0; t < 8; ++t) {
                    const int idx = symfold(2 * j - 6 + t, SIGLEN);
                    aa = fmaf(xr[idx], LO[t], aa);
                }
                dstA[SWZ(j - BDST)] = aa;
            }
        }
    }
}

template<int N, int BASE, int P0>
__device__ __forceinline__ void pool64(const float* __restrict__ buf,
                                       float* __restrict__ dst, int tid) {
    const int p = P0 + (tid >> 3), sub = tid & 7;
    const int s = (p * N) >> 7;
    const int e = ((p + 1) * N + 127) >> 7;
    float acc = 0.f;
    for (int t = s + sub; t < e; t += 8) acc += buf[SWZ(t - BASE)];
    acc += __shfl_xor(acc, 1);
    acc += __shfl_xor(acc, 2);
    acc += __shfl_xor(acc, 4);
    if (sub == 0) dst[p] = acc / (float)(e - s);
}

template<int B>
__device__ __forceinline__ void dwt_body(const float* __restrict__ xr,
                                         float* __restrict__ pr,
                                         float* __restrict__ A, float* __restrict__ Bb,
                                         float* __restrict__ D1, float* __restrict__ D2,
                                         int tid) {
    constexpr int p0 = B * 64;
    constexpr int sP5 = (p0 * N5) >> 7, eP5 = ((p0 + 64) * N5 + 127) >> 7;
    constexpr int sP4 = (p0 * N4) >> 7, eP4 = ((p0 + 64) * N4 + 127) >> 7;
    constexpr int sP3 = (p0 * N3) >> 7, eP3 = ((p0 + 64) * N3 + 127) >> 7;
    constexpr int sP2 = (p0 * N2) >> 7, eP2 = ((p0 + 64) * N2 + 127) >> 7;
    constexpr int s5 = sP5, e5 = cmin(eP5, N5);
    constexpr int s4 = cmax(cmin(sP4, 2 * s5 - 6), 0);
    constexpr int e4 = cmin(cmax(eP4, 2 * e5), N4);
    constexpr int s3 = cmax(cmin(sP3, 2 * s4 - 6), 0);
    constexpr int e3 = cmin(cmax(eP3, 2 * e4), N3);
    constexpr int s2 = cmax(cmin(sP2, 2 * s3 - 6), 0);
    constexpr int e2 = cmin(cmax(eP2, 2 * e3), N2);
    constexpr int s1 = cmax(2 * s2 - 6, 0);
    constexpr int e1 = cmin(2 * e2, N1);
    constexpr int b1 = (s1 & ~3) - 8, b2 = (s2 & ~3) - 8, b3 = (s3 & ~3) - 8;
    constexpr int b4 = (s4 & ~3) - 8, b5 = (s5 & ~3) - 8;

    dwt_l1<s1, e1, b1>(xr, A, tid);
    __syncthreads();
    dwt_chunk<s1, e1, b1, N1, s2, e2, b2>(A, Bb, D1, tid);
    __syncthreads();
    dwt_chunk<s2, e2, b2, N2, s3, e3, b3>(Bb, A, D2, tid);
    pool64<N2, b2, p0>(D1, pr + 4 * POOLP, tid);
    __syncthreads();
    dwt_chunk<s3, e3, b3, N3, s4, e4, b4>(A, Bb, D1, tid);
    pool64<N3, b3, p0>(D2, pr + 3 * POOLP, tid);
    __syncthreads();
    dwt_chunk<s4, e4, b4, N4, s5, e5, b5>(Bb, A, D2, tid);
    pool64<N4, b4, p0>(D1, pr + 2 * POOLP, tid);
    __syncthreads();
    pool64<N5, b5, p0>(A,  pr + 0 * POOLP, tid);
    pool64<N5, b5, p0>(D2, pr + 1 * POOLP, tid);
}

__global__ __launch_bounds__(NTHR, 4) void dwt_pool_kernel(const float* __restrict__ x,
                                                           float* __restrict__ pooled) {
    __shared__ __align__(16) float A[4192];
    __shared__ __align__(16) float Bb[2144];
    __shared__ __align__(16) float D1[2144];
    __shared__ __align__(16) float D2[1088];
    const int tid = threadIdx.x;
    const int row = blockIdx.x >> 1;
    const float* __restrict__ xr = x + (size_t)row * SIGLEN;
    float* __restrict__ pr = pooled + (size_t)row * COMB;
    if (blockIdx.x & 1) dwt_body<1>(xr, pr, A, Bb, D1, D2, tid);
    else                dwt_body<0>(xr, pr, A, Bb, D1, D2, tid);
}

// ---------------- MLP (unchanged from round 8) ----------------

#define LW_PAIRS (5 * 128 * 128 / 2)
#define FW_PAIRS (512 * 640 / 2)

__global__ __launch_bounds__(256) void pack_w(const float* __restrict__ lw,
                                              const float* __restrict__ fw,
                                              h2* __restrict__ lwh,
                                              h2* __restrict__ fwh) {
    const int i = blockIdx.x * 256 + threadIdx.x;
    if (i < LW_PAIRS) {
        const float2 v = reinterpret_cast<const float2*>(lw)[i];
        lwh[i] = __builtin_amdgcn_cvt_pkrtz(v.x, v.y);
    } else if (i < LW_PAIRS + FW_PAIRS) {
        const float2 v = reinterpret_cast<const float2*>(fw)[i - LW_PAIRS];
        fwh[i - LW_PAIRS] = __builtin_amdgcn_cvt_pkrtz(v.x, v.y);
    }
}

__global__ __launch_bounds__(1024, 4) void mlp_kernel(const float* __restrict__ pooled,
                                                      const h2* __restrict__ lwh,
                                                      const float* __restrict__ lb,
                                                      const h2* __restrict__ fwh,
                                                      const float* __restrict__ fb,
                                                      float* __restrict__ out) {
    __shared__ h2 sph[8][COMB / 2];
    __shared__ h2 sch[8][COMB / 2];
    const int tid = threadIdx.x;
    const int r0 = blockIdx.x * 8;

    const float2* __restrict__ srcp = reinterpret_cast<const float2*>(pooled + (size_t)r0 * COMB);
    for (int i = tid; i < 8 * (COMB / 2); i += 1024) {
        const float2 v = srcp[i];
        (&sph[0][0])[i] = __builtin_amdgcn_cvt_pkrtz(v.x, v.y);
    }
    __syncthreads();

    for (int idx = tid; idx < COMB * 2; idx += 1024) {
        const int c = idx >> 1, rh = (idx & 1) * 4;
        const h2* __restrict__ w = lwh + (size_t)c * 64;
        const int lb2 = (c >> 7) * 64;
        const float bias = lb[c];
        float acc[4] = {bias, bias, bias, bias};
        for (int t2 = 0; t2 < 64; t2 += 4) {
            const float4 wraw = *reinterpret_cast<const float4*>(w + t2);
            const h2 w0 = __builtin_bit_cast(h2, wraw.x);
            const h2 w1 = __builtin_bit_cast(h2, wraw.y);
            const h2 w2 = __builtin_bit_cast(h2, wraw.z);
            const h2 w3 = __builtin_bit_cast(h2, wraw.w);
#pragma unroll
            for (int r = 0; r < 4; ++r) {
                const float4 praw = *reinterpret_cast<const float4*>(&sph[rh + r][lb2 + t2]);
                acc[r] = __builtin_amdgcn_fdot2(__builtin_bit_cast(h2, praw.x), w0, acc[r], false);
                acc[r] = __builtin_amdgcn_fdot2(__builtin_bit_cast(h2, praw.y), w1, acc[r], false);
                acc[r] = __builtin_amdgcn_fdot2(__builtin_bit_cast(h2, praw.z), w2, acc[r], false);
                acc[r] = __builtin_amdgcn_fdot2(__builtin_bit_cast(h2, praw.w), w3, acc[r], false);
            }
        }
        __fp16* __restrict__ schf = reinterpret_cast<__fp16*>(&sch[0][0]);
#pragma unroll
        for (int r = 0; r < 4; ++r) schf[(rh + r) * COMB + c] = (__fp16)fmaxf(acc[r], 0.f);
    }
    __syncthreads();

    {
        const int c = tid >> 1, rh = (tid & 1) * 4;
        const h2* __restrict__ w = fwh + (size_t)c * (COMB / 2);
        const float bias = fb[c];
        float acc[4] = {bias, bias, bias, bias};
        for (int t2 = 0; t2 < COMB / 2; t2 += 4) {
            const float4 wraw = *reinterpret_cast<const float4*>(w + t2);
            const h2 w0 = __builtin_bit_cast(h2, wraw.x);
            const h2 w1 = __builtin_bit_cast(h2, wraw.y);
            const h2 w2 = __builtin_bit_cast(h2, wraw.z);
            const h2 w3 = __builtin_bit_cast(h2, wraw.w);
#pragma unroll
            for (int r = 0; r < 4; ++r) {
                const float4 craw = *reinterpret_cast<const float4*>(&sch[rh + r][t2]);
                acc[r] = __builtin_amdgcn_fdot2(__builtin_bit_cast(h2, craw.x), w0, acc[r], false);
                acc[r] = __builtin_amdgcn_fdot2(__builtin_bit_cast(h2, craw.y), w1, acc[r], false);
                acc[r] = __builtin_amdgcn_fdot2(__builtin_bit_cast(h2, craw.z), w2, acc[r], false);
                acc[r] = __builtin_amdgcn_fdot2(__builtin_bit_cast(h2, craw.w), w3, acc[r], false);
            }
        }
#pragma unroll
        for (int r = 0; r < 4; ++r) {
            out[(size_t)(r0 + rh + r) * OUTD + c] = fmaxf(acc[r], 0.f);
        }
    }
}

__global__ __launch_bounds__(512) void mlp_kernel_fb(const float* __restrict__ pooled,
                                                     const float* __restrict__ lw,
                                                     const float* __restrict__ lb,
                                                     const float* __restrict__ fw,
                                                     const float* __restrict__ fb,
                                                     float* __restrict__ out) {
    __shared__ h2 sph[8][COMB / 2];
    __shared__ h2 sch[8][COMB / 2];
    const int tid = threadIdx.x;
    const int r0 = blockIdx.x * 8;
    const float2* __restrict__ srcp = reinterpret_cast<const float2*>(pooled + (size_t)r0 * COMB);
    for (int i = tid; i < 8 * (COMB / 2); i += 512) {
        const float2 v = srcp[i];
        (&sph[0][0])[i] = __builtin_amdgcn_cvt_pkrtz(v.x, v.y);
    }
    __syncthreads();
    for (int c = tid; c < COMB; c += 512) {
        const float* __restrict__ w = lw + (size_t)c * POOLP;
        const int lb2 = (c >> 7) * (POOLP / 2);
        const float bias = lb[c];
        float acc[8];
#pragma unroll
        for (int r = 0; r < 8; ++r) acc[r] = bias;
        for (int t2 = 0; t2 < POOLP / 2; t2 += 4) {
            const float4 wa = *reinterpret_cast<const float4*>(w + t2 * 2);
            const float4 wb = *reinterpret_cast<const float4*>(w + t2 * 2 + 4);
            const h2 w0 = __builtin_amdgcn_cvt_pkrtz(wa.x, wa.y);
            const h2 w1 = __builtin_amdgcn_cvt_pkrtz(wa.z, wa.w);
            const h2 w2 = __builtin_amdgcn_cvt_pkrtz(wb.x, wb.y);
            const h2 w3 = __builtin_amdgcn_cvt_pkrtz(wb.z, wb.w);
#pragma unroll
            for (int r = 0; r < 8; ++r) {
                const float4 raw = *reinterpret_cast<const float4*>(&sph[r][lb2 + t2]);
                acc[r] = __builtin_amdgcn_fdot2(__builtin_bit_cast(h2, raw.x), w0, acc[r], false);
                acc[r] = __builtin_amdgcn_fdot2(__builtin_bit_cast(h2, raw.y), w1, acc[r], false);
                acc[r] = __builtin_amdgcn_fdot2(__builtin_bit_cast(h2, raw.z), w2, acc[r], false);
                acc[r] = __builtin_amdgcn_fdot2(__builtin_bit_cast(h2, raw.w), w3, acc[r], false);
            }
        }
        __fp16* __restrict__ schf = reinterpret_cast<__fp16*>(&sch[0][0]);
#pragma unroll
        for (int r = 0; r < 8; ++r) schf[r * COMB + c] = (__fp16)fmaxf(acc[r], 0.f);
    }
    __syncthreads();
    {
        const int j = tid;
        const float* __restrict__ w = fw + (size_t)j * COMB;
        const float bias = fb[j];
        float acc[8];
#pragma unroll
        for (int r = 0; r < 8; ++r) acc[r] = bias;
        for (int t2 = 0; t2 < COMB / 2; t2 += 4) {
            const float4 wa = *reinterpret_cast<const float4*>(w + t2 * 2);
            const float4 wb = *reinterpret_cast<const float4*>(w + t2 * 2 + 4);
            const h2 w0 = __builtin_amdgcn_cvt_pkrtz(wa.x, wa.y);
            const h2 w1 = __builtin_amdgcn_cvt_pkrtz(wa.z, wa.w);
            const h2 w2 = __builtin_amdgcn_cvt_pkrtz(wb.x, wb.y);
            const h2 w3 = __builtin_amdgcn_cvt_pkrtz(wb.z, wb.w);
#pragma unroll
            for (int r = 0; r < 8; ++r) {
                const float4 raw = *reinterpret_cast<const float4*>(&sch[r][t2]);
                acc[r] = __builtin_amdgcn_fdot2(__builtin_bit_cast(h2, raw.x), w0, acc[r], false);
                acc[r] = __builtin_amdgcn_fdot2(__builtin_bit_cast(h2, raw.y), w1, acc[r], false);
                acc[r] = __builtin_amdgcn_fdot2(__builtin_bit_cast(h2, raw.z), w2, acc[r], false);
                acc[r] = __builtin_amdgcn_fdot2(__builtin_bit_cast(h2, raw.w), w3, acc[r], false);
            }
        }
#pragma unroll
        for (int r = 0; r < 8; ++r) {
            out[(size_t)(r0 + r) * OUTD + j] = fmaxf(acc[r], 0.f);
        }
    }
}

extern "C" void kernel_launch(void* const* d_in, const int* in_sizes, int n_in,
                              void* d_out, int out_size, void* d_ws, size_t ws_size,
                              hipStream_t stream) {
    const float* x  = (const float*)d_in[0];
    const float* lw = (const float*)d_in[1];
    const float* lb = (const float*)d_in[2];
    const float* fw = (const float*)d_in[3];
    const float* fb = (const float*)d_in[4];
    float* out = (float*)d_out;

    char* base = (char*)d_ws;
    const size_t POOLED_B = (size_t)BATCH * COMB * 4;            // 5,242,880
    const size_t LWH_B    = (size_t)LW_PAIRS * 4;                // 163,840
    const size_t FWH_B    = (size_t)FW_PAIRS * 4;                // 655,360
    const size_t WT_B     = (size_t)COMB * WLEN * 2;             // 655,360

    float* pooled = (float*)base;
    h2*  lwh  = (h2*)(base + POOLED_B);
    h2*  fwh  = (h2*)(base + POOLED_B + LWH_B);
    h2*  wt   = (h2*)(base + POOLED_B + LWH_B + FWH_B);

    const size_t NEED_MLP    = POOLED_B + LWH_B + FWH_B;
    const size_t NEED_BANDED = NEED_MLP + WT_B;

    if (ws_size >= NEED_BANDED) {
        build_w<<<COMB, 128, 0, stream>>>(wt);
        banded_kernel<<<BATCH, 512, 0, stream>>>(x, wt, pooled);
    } else {
        dwt_pool_kernel<<<BATCH * 2, NTHR, 0, stream>>>(x, pooled);
    }

    if (ws_size >= NEED_MLP) {
        pack_w<<<(LW_PAIRS + FW_PAIRS + 255) / 256, 256, 0, stream>>>(lw, fw, lwh, fwh);
        mlp_kernel<<<BATCH / 8, 1024, 0, stream>>>(pooled, lwh, lb, fwh, fb, out);
    } else {
        mlp_kernel_fb<<<BATCH / 8, 512, 0, stream>>>(pooled, lw, lb, fw, fb, out);
    }
}

// Round 17
// 175.217 us; speedup vs baseline: 2.1209x; 2.1209x over previous
//
#include <hip/hip_runtime.h>

// WaveletFeatureExtractor: db4 wavedec (5 levels, symmetric pad) -> adaptive pool 128
// -> per-level 128x128 MLP (ReLU) -> fused 640->512 MLP (ReLU).
//
// Round 17: staged-w banded kernel, spill-proof. r16's WRITE_SIZE=326MB exposed
// scratch spill of tile registers held across __syncthreads under control flow.
// Fix: double-buffered wtile (2x16KB, 16 rows/pass, 40 passes); next-tile loads
// issued at pass start (unconditional, clamped), ds_write BEFORE the barrier ->
// register liveness confined to the compute region (8 VGPR). Pass p reads
// buf[cur], stages buf[cur^1]; end-of-pass barrier orders everything.
// Dot: 32 lanes/output, 2 granules/lane, pure LDS (r16-verified layout,
// conflicts 180K). Analytic sx (verified r16). build_w adjoint (verified r13).
// r10-cascade fallback; mlp = r8.

#define BATCH   2048
#define SIGLEN  16384
#define N1      8195
#define N2      4101
#define N3      2054
#define N4      1030
#define N5      518
#define POOLP   128
#define COMB    640
#define OUTD    512
#define WLEN    512   // 64 granules of 8 f16; true window <= 388

typedef __fp16 h2 __attribute__((ext_vector_type(2)));

__device__ constexpr float LO[8] = {
     0.2303778133088965f,   0.7148465705529157f,   0.6308807679298589f,
    -0.027983769416859854f, -0.18703481171909309f,  0.030841381835560764f,
     0.0328830116668852f,  -0.010597401785069032f };
__device__ constexpr float HI[8] = {
    -0.010597401785069032f, -0.0328830116668852f,   0.030841381835560764f,
     0.18703481171909309f,  -0.027983769416859854f, -0.6308807679298589f,
     0.7148465705529157f,  -0.2303778133088965f };

// ---------------- build_w: adjoint cascade -> banded rows (verified r13) ------
__global__ __launch_bounds__(128) void build_w(h2* __restrict__ wt)  // [640][WLEN/2]
{
    __shared__ float g0[512], g1[512];
    const int c = blockIdx.x;
    const int slot = c >> 7, p = c & 127;
    const int tid = threadIdx.x;

    const int bandN[5] = {N5, N5, N4, N3, N2};
    const int M = bandN[slot];
    const int s = (p * M) >> 7;
    const int e = ((p + 1) * M + 127) >> 7;

    for (int i = tid; i < 512; i += 128) { g0[i] = 0.f; g1[i] = 0.f; }
    __syncthreads();
    const float inv = 1.f / (float)(e - s);
    for (int i = tid; i < e - s; i += 128) g0[i] = inv;
    __syncthreads();

    float* cur = g0;
    float* nxt = g1;
    int ws = s, we = e;

    const int nsteps = (slot <= 1) ? 5 : (6 - slot);     // 5,5,4,3,2
    const int nins[5] = {N4, N3, N2, N1, SIGLEN};
    const int start = 5 - nsteps;

    for (int st = 0; st < nsteps; ++st) {
        const int Nin = nins[start + st];
        const bool useHI = (st == 0 && slot >= 1);
        const int nws = (2 * ws - 6 < 0) ? 0 : (2 * ws - 6);
        const int nwe = (2 * we < Nin) ? (2 * we) : Nin;
        for (int i = tid; i < nwe - nws; i += 128) nxt[i] = 0.f;
        __syncthreads();
        for (int t = 0; t < 8; ++t) {
            const float f = useHI ? HI[t] : LO[t];
            for (int j = ws + tid; j < we; j += 128) {
                int idx = 2 * j - 6 + t;
                idx = (idx < 0) ? (-1 - idx) : idx;
                idx = (idx >= Nin) ? (2 * Nin - 1 - idx) : idx;
                nxt[idx - nws] += f * cur[j - ws];
            }
            __syncthreads();
        }
        float* tmp = cur; cur = nxt; nxt = tmp;
        ws = nws; we = nwe;
    }

    const int sx0 = ws & ~7;                 // 8-elem aligned; kernel recomputes this
    __fp16* wrow = reinterpret_cast<__fp16*>(wt + (size_t)c * (WLEN / 2));
    for (int i = tid; i < WLEN; i += 128) {
        const int idx = sx0 + i;
        const float v = (idx >= ws && idx < we) ? cur[idx - ws] : 0.f;
        wrow[i] = (__fp16)v;
    }
}

// ---------- staged-w banded dot: 40 passes x 16 outputs, dbuf LDS tiles ----
__global__ __launch_bounds__(512) void banded_kernel(const float* __restrict__ x,
                                                     const h2* __restrict__ wt,
                                                     float* __restrict__ pooled) {
    __shared__ __align__(16) unsigned int xs_u[SIGLEN / 2 + 256]; // f16 pairs + 1KB zero pad
    __shared__ __align__(16) float4 wtile[2][1024];               // 2 x (16 rows x 512 f16) = 2x16KB

    const int tid = threadIdx.x;
    const int row = blockIdx.x;
    const float* __restrict__ xr = x + (size_t)row * SIGLEN;

    // stage x -> f16 pairs
    for (int i = tid; i < SIGLEN / 4; i += 512) {
        const float4 v = *reinterpret_cast<const float4*>(xr + 4 * i);
        const h2 p0 = __builtin_amdgcn_cvt_pkrtz(v.x, v.y);
        const h2 p1 = __builtin_amdgcn_cvt_pkrtz(v.z, v.w);
        uint2 pk;
        pk.x = __builtin_bit_cast(unsigned int, p0);
        pk.y = __builtin_bit_cast(unsigned int, p1);
        *reinterpret_cast<uint2*>(xs_u + 2 * i) = pk;
    }
    if (tid < 256) xs_u[SIGLEN / 2 + tid] = 0u;

    // stage tile 0 (contiguous 16KB)
    const float4* __restrict__ wt4 = reinterpret_cast<const float4*>(wt);
    wtile[0][tid] = wt4[tid];
    wtile[0][tid + 512] = wt4[tid + 512];
    __syncthreads();

    const float* __restrict__ xs_f = reinterpret_cast<const float*>(xs_u);
    const int sub = tid & 31;
    const int cb  = tid >> 5;                 // 0..15

    int cur = 0;
    for (int pass = 0; pass < 40; ++pass) {
        // issue next tile's loads up-front (clamped -> unconditional, no spill-prone CF)
        const int nxt = (pass + 1 < 40) ? (pass + 1) : 39;
        const float4* __restrict__ nsrc = wt4 + (size_t)nxt * 1024;
        const float4 s0 = nsrc[tid];
        const float4 s1 = nsrc[tid + 512];

        // compute 16 outputs from wtile[cur] (analytic sx, verified r16)
        const int c = pass * 16 + cb;
        const int slot = c >> 7, p = c & 127;
        const int M = (slot <= 1) ? N5 : (slot == 2 ? N4 : (slot == 3 ? N3 : N2));
        const int nst = (slot <= 1) ? 5 : (6 - slot);
        int ws = (p * M) >> 7;
#pragma unroll
        for (int k = 0; k < 5; ++k) {
            if (k < nst) { int t = 2 * ws - 6; ws = (t < 0) ? 0 : t; }
        }
        const int sxh = (ws & ~7) >> 1;       // float-index, 16B-aligned

        const float* __restrict__ wrow_f = reinterpret_cast<const float*>(&wtile[cur][cb * 64]);
        float acc = 0.f;
#pragma unroll
        for (int i = 0; i < 2; ++i) {
            const int g = sub + 32 * i;
            const float4 xv = *reinterpret_cast<const float4*>(xs_f + sxh + 4 * g);
            const float4 wv = *reinterpret_cast<const float4*>(wrow_f + 4 * g);
            acc = __builtin_amdgcn_fdot2(__builtin_bit_cast(h2, xv.x), __builtin_bit_cast(h2, wv.x), acc, false);
            acc = __builtin_amdgcn_fdot2(__builtin_bit_cast(h2, xv.y), __builtin_bit_cast(h2, wv.y), acc, false);
            acc = __builtin_amdgcn_fdot2(__builtin_bit_cast(h2, xv.z), __builtin_bit_cast(h2, wv.z), acc, false);
            acc = __builtin_amdgcn_fdot2(__builtin_bit_cast(h2, xv.w), __builtin_bit_cast(h2, wv.w), acc, false);
        }
        acc += __shfl_xor(acc, 1);
        acc += __shfl_xor(acc, 2);
        acc += __shfl_xor(acc, 4);
        acc += __shfl_xor(acc, 8);
        acc += __shfl_xor(acc, 16);
        if (sub == 0) pooled[(size_t)row * COMB + c] = acc;

        // write staged tile into the other buffer BEFORE the barrier
        wtile[cur ^ 1][tid] = s0;
        wtile[cur ^ 1][tid + 512] = s1;
        __syncthreads();
        cur ^= 1;
    }
}

// ---------------- Fallback dwt cascade (round 10, proven) ----------------

#define SWZ(i) ((i) ^ ((((i) >> 5) & 7) << 2))
#define NTHR 512

__device__ __forceinline__ int symfold(int idx, int n) {
    idx = (idx < 0) ? (-1 - idx) : idx;
    idx = (idx >= n) ? (2 * n - 1 - idx) : idx;
    return idx;
}
constexpr int cmin(int a, int b) { return a < b ? a : b; }
constexpr int cmax(int a, int b) { return a > b ? a : b; }

template<int SS, int SE, int BSRC, int NSRC, int S, int E, int BDST>
__device__ __forceinline__ void dwt_chunk(const float* __restrict__ src,
                                          float* __restrict__ dstA,
                                          float* __restrict__ dstD, int tid) {
    for (int j0 = (S & ~3) + tid * 4; j0 < E; j0 += NTHR * 4) {
        const int rb = 2 * j0 - 8;
        if ((rb >= SS) && (2 * j0 + 7 <= SE - 1) && (j0 + 4 <= E)) {
            const int lrb = rb - BSRC;
            const float4 v0 = *reinterpret_cast<const float4*>(src + SWZ(lrb));
            const float4 v1 = *reinterpret_cast<const float4*>(src + SWZ(lrb + 4));
            const float4 v2 = *reinterpret_cast<const float4*>(src + SWZ(lrb + 8));
            const float4 v3 = *reinterpret_cast<const float4*>(src + SWZ(lrb + 12));
            float w[16];
            w[0]=v0.x;  w[1]=v0.y;  w[2]=v0.z;  w[3]=v0.w;
            w[4]=v1.x;  w[5]=v1.y;  w[6]=v1.z;  w[7]=v1.w;
            w[8]=v2.x;  w[9]=v2.y;  w[10]=v2.z; w[11]=v2.w;
            w[12]=v3.x; w[13]=v3.y; w[14]=v3.z; w[15]=v3.w;
            float a[4], d[4];
#pragma unroll
            for (int k = 0; k < 4; ++k) {
                float aa = 0.f, dd = 0.f;
#pragma unroll
                for (int t = 0; t < 8; ++t) {
                    const float v = w[2 + 2 * k + t];
                    aa = fmaf(v, LO[t], aa);
                    dd = fmaf(v, HI[t], dd);
                }
                a[k] = aa; d[k] = dd;
            }
            const int ds = j0 - BDST;
            *reinterpret_cast<float4*>(dstA + SWZ(ds)) = make_float4(a[0], a[1], a[2], a[3]);
            *reinterpret_cast<float4*>(dstD + SWZ(ds)) = make_float4(d[0], d[1], d[2], d[3]);
        } else {
            for (int k = 0; k < 4; ++k) {
                const int j = j0 + k;
                if (j < S || j >= E) continue;
                float aa = 0.f, dd = 0.f;
#pragma unroll
                for (int t = 0; t < 8; ++t) {
                    const int idx = symfold(2 * j - 6 + t, NSRC);
                    const float v = src[SWZ(idx - BSRC)];
                    aa = fmaf(v, LO[t], aa);
                    dd = fmaf(v, HI[t], dd);
                }
                dstA[SWZ(j - BDST)] = aa;
                dstD[SWZ(j - BDST)] = dd;
            }
        }
    }
}

template<int S, int E, int BDST>
__device__ __forceinline__ void dwt_l1(const float* __restrict__ xr,
                                       float* __restrict__ dstA, int tid) {
    for (int j0 = (S & ~3) + tid * 4; j0 < E; j0 += NTHR * 4) {
        const int rb = 2 * j0 - 8;
        if ((rb >= 0) && (2 * j0 + 7 <= SIGLEN - 1) && (j0 + 4 <= E)) {
            const float4* s4 = reinterpret_cast<const float4*>(xr + rb);
            const float4 v0 = s4[0], v1 = s4[1], v2 = s4[2], v3 = s4[3];
            float w[16];
            w[0]=v0.x;  w[1]=v0.y;  w[2]=v0.z;  w[3]=v0.w;
            w[4]=v1.x;  w[5]=v1.y;  w[6]=v1.z;  w[7]=v1.w;
            w[8]=v2.x;  w[9]=v2.y;  w[10]=v2.z; w[11]=v2.w;
            w[12]=v3.x; w[13]=v3.y; w[14]=v3.z; w[15]=v3.w;
            float a[4];
#pragma unroll
            for (int k = 0; k < 4; ++k) {
                float aa = 0.f;
#pragma unroll
                for (int t = 0; t < 8; ++t) aa = fmaf(w[2 + 2 * k + t], LO[t], aa);
                a[k] = aa;
            }
            *reinterpret_cast<float4*>(dstA + SWZ(j0 - BDST)) = make_float4(a[0], a[1], a[2], a[3]);
        } else {
            for (int k = 0; k < 4; ++k) {
                const int j = j0 + k;
                if (j < S || j >= E) continue;
                float aa = 0.f;
#pragma unroll
                for (int t = 0; t < 8; ++t) {
                    const int idx = symfold(2 * j - 6 + t, SIGLEN);
                    aa = fmaf(xr[idx], LO[t], aa);
                }
                dstA[SWZ(j - BDST)] = aa;
            }
        }
    }
}

template<int N, int BASE, int P0>
__device__ __forceinline__ void pool64(const float* __restrict__ buf,
                                       float* __restrict__ dst, int tid) {
    const int p = P0 + (tid >> 3), sub = tid & 7;
    const int s = (p * N) >> 7;
    const int e = ((p + 1) * N + 127) >> 7;
    float acc = 0.f;
    for (int t = s + sub; t < e; t += 8) acc += buf[SWZ(t - BASE)];
    acc += __shfl_xor(acc, 1);
    acc += __shfl_xor(acc, 2);
    acc += __shfl_xor(acc, 4);
    if (sub == 0) dst[p] = acc / (float)(e - s);
}

template<int B>
__device__ __forceinline__ void dwt_body(const float* __restrict__ xr,
                                         float* __restrict__ pr,
                                         float* __restrict__ A, float* __restrict__ Bb,
                                         float* __restrict__ D1, float* __restrict__ D2,
                                         int tid) {
    constexpr int p0 = B * 64;
    constexpr int sP5 = (p0 * N5) >> 7, eP5 = ((p0 + 64) * N5 + 127) >> 7;
    constexpr int sP4 = (p0 * N4) >> 7, eP4 = ((p0 + 64) * N4 + 127) >> 7;
    constexpr int sP3 = (p0 * N3) >> 7, eP3 = ((p0 + 64) * N3 + 127) >> 7;
    constexpr int sP2 = (p0 * N2) >> 7, eP2 = ((p0 + 64) * N2 + 127) >> 7;
    constexpr int s5 = sP5, e5 = cmin(eP5, N5);
    constexpr int s4 = cmax(cmin(sP4, 2 * s5 - 6), 0);
    constexpr int e4 = cmin(cmax(eP4, 2 * e5), N4);
    constexpr int s3 = cmax(cmin(sP3, 2 * s4 - 6), 0);
    constexpr int e3 = cmin(cmax(eP3, 2 * e4), N3);
    constexpr int s2 = cmax(cmin(sP2, 2 * s3 - 6), 0);
    constexpr int e2 = cmin(cmax(eP2, 2 * e3), N2);
    constexpr int s1 = cmax(2 * s2 - 6, 0);
    constexpr int e1 = cmin(2 * e2, N1);
    constexpr int b1 = (s1 & ~3) - 8, b2 = (s2 & ~3) - 8, b3 = (s3 & ~3) - 8;
    constexpr int b4 = (s4 & ~3) - 8, b5 = (s5 & ~3) - 8;

    dwt_l1<s1, e1, b1>(xr, A, tid);
    __syncthreads();
    dwt_chunk<s1, e1, b1, N1, s2, e2, b2>(A, Bb, D1, tid);
    __syncthreads();
    dwt_chunk<s2, e2, b2, N2, s3, e3, b3>(Bb, A, D2, tid);
    pool64<N2, b2, p0>(D1, pr + 4 * POOLP, tid);
    __syncthreads();
    dwt_chunk<s3, e3, b3, N3, s4, e4, b4>(A, Bb, D1, tid);
    pool64<N3, b3, p0>(D2, pr + 3 * POOLP, tid);
    __syncthreads();
    dwt_chunk<s4, e4, b4, N4, s5, e5, b5>(Bb, A, D2, tid);
    pool64<N4, b4, p0>(D1, pr + 2 * POOLP, tid);
    __syncthreads();
    pool64<N5, b5, p0>(A,  pr + 0 * POOLP, tid);
    pool64<N5, b5, p0>(D2, pr + 1 * POOLP, tid);
}

__global__ __launch_bounds__(NTHR, 4) void dwt_pool_kernel(const float* __restrict__ x,
                                                           float* __restrict__ pooled) {
    __shared__ __align__(16) float A[4192];
    __shared__ __align__(16) float Bb[2144];
    __shared__ __align__(16) float D1[2144];
    __shared__ __align__(16) float D2[1088];
    const int tid = threadIdx.x;
    const int row = blockIdx.x >> 1;
    const float* __restrict__ xr = x + (size_t)row * SIGLEN;
    float* __restrict__ pr = pooled + (size_t)row * COMB;
    if (blockIdx.x & 1) dwt_body<1>(xr, pr, A, Bb, D1, D2, tid);
    else                dwt_body<0>(xr, pr, A, Bb, D1, D2, tid);
}

// ---------------- MLP (unchanged from round 8) ----------------

#define LW_PAIRS (5 * 128 * 128 / 2)
#define FW_PAIRS (512 * 640 / 2)

__global__ __launch_bounds__(256) void pack_w(const float* __restrict__ lw,
                                              const float* __restrict__ fw,
                                              h2* __restrict__ lwh,
                                              h2* __restrict__ fwh) {
    const int i = blockIdx.x * 256 + threadIdx.x;
    if (i < LW_PAIRS) {
        const float2 v = reinterpret_cast<const float2*>(lw)[i];
        lwh[i] = __builtin_amdgcn_cvt_pkrtz(v.x, v.y);
    } else if (i < LW_PAIRS + FW_PAIRS) {
        const float2 v = reinterpret_cast<const float2*>(fw)[i - LW_PAIRS];
        fwh[i - LW_PAIRS] = __builtin_amdgcn_cvt_pkrtz(v.x, v.y);
    }
}

__global__ __launch_bounds__(1024, 4) void mlp_kernel(const float* __restrict__ pooled,
                                                      const h2* __restrict__ lwh,
                                                      const float* __restrict__ lb,
                                                      const h2* __restrict__ fwh,
                                                      const float* __restrict__ fb,
                                                      float* __restrict__ out) {
    __shared__ h2 sph[8][COMB / 2];
    __shared__ h2 sch[8][COMB / 2];
    const int tid = threadIdx.x;
    const int r0 = blockIdx.x * 8;

    const float2* __restrict__ srcp = reinterpret_cast<const float2*>(pooled + (size_t)r0 * COMB);
    for (int i = tid; i < 8 * (COMB / 2); i += 1024) {
        const float2 v = srcp[i];
        (&sph[0][0])[i] = __builtin_amdgcn_cvt_pkrtz(v.x, v.y);
    }
    __syncthreads();

    for (int idx = tid; idx < COMB * 2; idx += 1024) {
        const int c = idx >> 1, rh = (idx & 1) * 4;
        const h2* __restrict__ w = lwh + (size_t)c * 64;
        const int lb2 = (c >> 7) * 64;
        const float bias = lb[c];
        float acc[4] = {bias, bias, bias, bias};
        for (int t2 = 0; t2 < 64; t2 += 4) {
            const float4 wraw = *reinterpret_cast<const float4*>(w + t2);
            const h2 w0 = __builtin_bit_cast(h2, wraw.x);
            const h2 w1 = __builtin_bit_cast(h2, wraw.y);
            const h2 w2 = __builtin_bit_cast(h2, wraw.z);
            const h2 w3 = __builtin_bit_cast(h2, wraw.w);
#pragma unroll
            for (int r = 0; r < 4; ++r) {
                const float4 praw = *reinterpret_cast<const float4*>(&sph[rh + r][lb2 + t2]);
                acc[r] = __builtin_amdgcn_fdot2(__builtin_bit_cast(h2, praw.x), w0, acc[r], false);
                acc[r] = __builtin_amdgcn_fdot2(__builtin_bit_cast(h2, praw.y), w1, acc[r], false);
                acc[r] = __builtin_amdgcn_fdot2(__builtin_bit_cast(h2, praw.z), w2, acc[r], false);
                acc[r] = __builtin_amdgcn_fdot2(__builtin_bit_cast(h2, praw.w), w3, acc[r], false);
            }
        }
        __fp16* __restrict__ schf = reinterpret_cast<__fp16*>(&sch[0][0]);
#pragma unroll
        for (int r = 0; r < 4; ++r) schf[(rh + r) * COMB + c] = (__fp16)fmaxf(acc[r], 0.f);
    }
    __syncthreads();

    {
        const int c = tid >> 1, rh = (tid & 1) * 4;
        const h2* __restrict__ w = fwh + (size_t)c * (COMB / 2);
        const float bias = fb[c];
        float acc[4] = {bias, bias, bias, bias};
        for (int t2 = 0; t2 < COMB / 2; t2 += 4) {
            const float4 wraw = *reinterpret_cast<const float4*>(w + t2);
            const h2 w0 = __builtin_bit_cast(h2, wraw.x);
            const h2 w1 = __builtin_bit_cast(h2, wraw.y);
            const h2 w2 = __builtin_bit_cast(h2, wraw.z);
            const h2 w3 = __builtin_bit_cast(h2, wraw.w);
#pragma unroll
            for (int r = 0; r < 4; ++r) {
                const float4 craw = *reinterpret_cast<const float4*>(&sch[rh + r][t2]);
                acc[r] = __builtin_amdgcn_fdot2(__builtin_bit_cast(h2, craw.x), w0, acc[r], false);
                acc[r] = __builtin_amdgcn_fdot2(__builtin_bit_cast(h2, craw.y), w1, acc[r], false);
                acc[r] = __builtin_amdgcn_fdot2(__builtin_bit_cast(h2, craw.z), w2, acc[r], false);
                acc[r] = __builtin_amdgcn_fdot2(__builtin_bit_cast(h2, craw.w), w3, acc[r], false);
            }
        }
#pragma unroll
        for (int r = 0; r < 4; ++r) {
            out[(size_t)(r0 + rh + r) * OUTD + c] = fmaxf(acc[r], 0.f);
        }
    }
}

__global__ __launch_bounds__(512) void mlp_kernel_fb(const float* __restrict__ pooled,
                                                     const float* __restrict__ lw,
                                                     const float* __restrict__ lb,
                                                     const float* __restrict__ fw,
                                                     const float* __restrict__ fb,
                                                     float* __restrict__ out) {
    __shared__ h2 sph[8][COMB / 2];
    __shared__ h2 sch[8][COMB / 2];
    const int tid = threadIdx.x;
    const int r0 = blockIdx.x * 8;
    const float2* __restrict__ srcp = reinterpret_cast<const float2*>(pooled + (size_t)r0 * COMB);
    for (int i = tid; i < 8 * (COMB / 2); i += 512) {
        const float2 v = srcp[i];
        (&sph[0][0])[i] = __builtin_amdgcn_cvt_pkrtz(v.x, v.y);
    }
    __syncthreads();
    for (int c = tid; c < COMB; c += 512) {
        const float* __restrict__ w = lw + (size_t)c * POOLP;
        const int lb2 = (c >> 7) * (POOLP / 2);
        const float bias = lb[c];
        float acc[8];
#pragma unroll
        for (int r = 0; r < 8; ++r) acc[r] = bias;
        for (int t2 = 0; t2 < POOLP / 2; t2 += 4) {
            const float4 wa = *reinterpret_cast<const float4*>(w + t2 * 2);
            const float4 wb = *reinterpret_cast<const float4*>(w + t2 * 2 + 4);
            const h2 w0 = __builtin_amdgcn_cvt_pkrtz(wa.x, wa.y);
            const h2 w1 = __builtin_amdgcn_cvt_pkrtz(wa.z, wa.w);
            const h2 w2 = __builtin_amdgcn_cvt_pkrtz(wb.x, wb.y);
            const h2 w3 = __builtin_amdgcn_cvt_pkrtz(wb.z, wb.w);
#pragma unroll
            for (int r = 0; r < 8; ++r) {
                const float4 raw = *reinterpret_cast<const float4*>(&sph[r][lb2 + t2]);
                acc[r] = __builtin_amdgcn_fdot2(__builtin_bit_cast(h2, raw.x), w0, acc[r], false);
                acc[r] = __builtin_amdgcn_fdot2(__builtin_bit_cast(h2, raw.y), w1, acc[r], false);
                acc[r] = __builtin_amdgcn_fdot2(__builtin_bit_cast(h2, raw.z), w2, acc[r], false);
                acc[r] = __builtin_amdgcn_fdot2(__builtin_bit_cast(h2, raw.w), w3, acc[r], false);
            }
        }
        __fp16* __restrict__ schf = reinterpret_cast<__fp16*>(&sch[0][0]);
#pragma unroll
        for (int r = 0; r < 8; ++r) schf[r * COMB + c] = (__fp16)fmaxf(acc[r], 0.f);
    }
    __syncthreads();
    {
        const int j = tid;
        const float* __restrict__ w = fw + (size_t)j * COMB;
        const float bias = fb[j];
        float acc[8];
#pragma unroll
        for (int r = 0; r < 8; ++r) acc[r] = bias;
        for (int t2 = 0; t2 < COMB / 2; t2 += 4) {
            const float4 wa = *reinterpret_cast<const float4*>(w + t2 * 2);
            const float4 wb = *reinterpret_cast<const float4*>(w + t2 * 2 + 4);
            const h2 w0 = __builtin_amdgcn_cvt_pkrtz(wa.x, wa.y);
            const h2 w1 = __builtin_amdgcn_cvt_pkrtz(wa.z, wa.w);
            const h2 w2 = __builtin_amdgcn_cvt_pkrtz(wb.x, wb.y);
            const h2 w3 = __builtin_amdgcn_cvt_pkrtz(wb.z, wb.w);
#pragma unroll
            for (int r = 0; r < 8; ++r) {
                const float4 raw = *reinterpret_cast<const float4*>(&sch[r][t2]);
                acc[r] = __builtin_amdgcn_fdot2(__builtin_bit_cast(h2, raw.x), w0, acc[r], false);
                acc[r] = __builtin_amdgcn_fdot2(__builtin_bit_cast(h2, raw.y), w1, acc[r], false);
                acc[r] = __builtin_amdgcn_fdot2(__builtin_bit_cast(h2, raw.z), w2, acc[r], false);
                acc[r] = __builtin_amdgcn_fdot2(__builtin_bit_cast(h2, raw.w), w3, acc[r], false);
            }
        }
#pragma unroll
        for (int r = 0; r < 8; ++r) {
            out[(size_t)(r0 + r) * OUTD + j] = fmaxf(acc[r], 0.f);
        }
    }
}

extern "C" void kernel_launch(void* const* d_in, const int* in_sizes, int n_in,
                              void* d_out, int out_size, void* d_ws, size_t ws_size,
                              hipStream_t stream) {
    const float* x  = (const float*)d_in[0];
    const float* lw = (const float*)d_in[1];
    const float* lb = (const float*)d_in[2];
    const float* fw = (const float*)d_in[3];
    const float* fb = (const float*)d_in[4];
    float* out = (float*)d_out;

    char* base = (char*)d_ws;
    const size_t POOLED_B = (size_t)BATCH * COMB * 4;            // 5,242,880
    const size_t LWH_B    = (size_t)LW_PAIRS * 4;                // 163,840
    const size_t FWH_B    = (size_t)FW_PAIRS * 4;                // 655,360
    const size_t WT_B     = (size_t)COMB * WLEN * 2;             // 655,360

    float* pooled = (float*)base;
    h2*  lwh  = (h2*)(base + POOLED_B);
    h2*  fwh  = (h2*)(base + POOLED_B + LWH_B);
    h2*  wt   = (h2*)(base + POOLED_B + LWH_B + FWH_B);

    const size_t NEED_MLP    = POOLED_B + LWH_B + FWH_B;
    const size_t NEED_BANDED = NEED_MLP + WT_B;

    if (ws_size >= NEED_BANDED) {
        build_w<<<COMB, 128, 0, stream>>>(wt);
        banded_kernel<<<BATCH, 512, 0, stream>>>(x, wt, pooled);
    } else {
        dwt_pool_kernel<<<BATCH * 2, NTHR, 0, stream>>>(x, pooled);
    }

    if (ws_size >= NEED_MLP) {
        pack_w<<<(LW_PAIRS + FW_PAIRS + 255) / 256, 256, 0, stream>>>(lw, fw, lwh, fwh);
        mlp_kernel<<<BATCH / 8, 1024, 0, stream>>>(pooled, lwh, lb, fwh, fb, out);
    } else {
        mlp_kernel_fb<<<BATCH / 8, 512, 0, stream>>>(pooled, lw, lb, fw, fb, out);
    }
}

// Round 18
// 89.932 us; speedup vs baseline: 4.1322x; 1.9483x over previous
//
#include <hip/hip_runtime.h>

// WaveletFeatureExtractor: db4 wavedec (5 levels, symmetric pad) -> adaptive pool 128
// -> per-level 128x128 MLP (ReLU) -> fused 640->512 MLP (ReLU).
//
// Round 18: revert to the proven r10 champion (cascade dwt 77us: 2 blocks/row,
// constexpr geometry via template<B>, XOR-swizzled LDS, lb(512,4) -> 4 blocks/CU)
// after the banded arc (r13-r17: 197/85/85/363/158) never beat it. One safe
// improvement: pool64 writes pooled as f16 (RTE) directly -- the mlp already
// round-trips pooled through cvt_pkrtz (RTZ), so this adds ZERO error while
// halving pooled traffic and deleting the mlp's convert pass.

#define BATCH   2048
#define SIGLEN  16384
#define N1      8195
#define N2      4101
#define N3      2054
#define N4      1030
#define N5      518
#define POOLP   128
#define COMB    640
#define OUTD    512
#define NTHR    512

#define SWZ(i) ((i) ^ ((((i) >> 5) & 7) << 2))

typedef __fp16 h2 __attribute__((ext_vector_type(2)));

__device__ constexpr float LO[8] = {
     0.2303778133088965f,   0.7148465705529157f,   0.6308807679298589f,
    -0.027983769416859854f, -0.18703481171909309f,  0.030841381835560764f,
     0.0328830116668852f,  -0.010597401785069032f };
__device__ constexpr float HI[8] = {
    -0.010597401785069032f, -0.0328830116668852f,   0.030841381835560764f,
     0.18703481171909309f,  -0.027983769416859854f, -0.6308807679298589f,
     0.7148465705529157f,  -0.2303778133088965f };

__device__ __forceinline__ int symfold(int idx, int n) {
    idx = (idx < 0) ? (-1 - idx) : idx;
    idx = (idx >= n) ? (2 * n - 1 - idx) : idx;
    return idx;
}
constexpr int cmin(int a, int b) { return a < b ? a : b; }
constexpr int cmax(int a, int b) { return a > b ? a : b; }

template<int SS, int SE, int BSRC, int NSRC, int S, int E, int BDST>
__device__ __forceinline__ void dwt_chunk(const float* __restrict__ src,
                                          float* __restrict__ dstA,
                                          float* __restrict__ dstD, int tid) {
    for (int j0 = (S & ~3) + tid * 4; j0 < E; j0 += NTHR * 4) {
        const int rb = 2 * j0 - 8;
        if ((rb >= SS) && (2 * j0 + 7 <= SE - 1) && (j0 + 4 <= E)) {
            const int lrb = rb - BSRC;
            const float4 v0 = *reinterpret_cast<const float4*>(src + SWZ(lrb));
            const float4 v1 = *reinterpret_cast<const float4*>(src + SWZ(lrb + 4));
            const float4 v2 = *reinterpret_cast<const float4*>(src + SWZ(lrb + 8));
            const float4 v3 = *reinterpret_cast<const float4*>(src + SWZ(lrb + 12));
            float w[16];
            w[0]=v0.x;  w[1]=v0.y;  w[2]=v0.z;  w[3]=v0.w;
            w[4]=v1.x;  w[5]=v1.y;  w[6]=v1.z;  w[7]=v1.w;
            w[8]=v2.x;  w[9]=v2.y;  w[10]=v2.z; w[11]=v2.w;
            w[12]=v3.x; w[13]=v3.y; w[14]=v3.z; w[15]=v3.w;
            float a[4], d[4];
#pragma unroll
            for (int k = 0; k < 4; ++k) {
                float aa = 0.f, dd = 0.f;
#pragma unroll
                for (int t = 0; t < 8; ++t) {
                    const float v = w[2 + 2 * k + t];
                    aa = fmaf(v, LO[t], aa);
                    dd = fmaf(v, HI[t], dd);
                }
                a[k] = aa; d[k] = dd;
            }
            const int ds = j0 - BDST;
            *reinterpret_cast<float4*>(dstA + SWZ(ds)) = make_float4(a[0], a[1], a[2], a[3]);
            *reinterpret_cast<float4*>(dstD + SWZ(ds)) = make_float4(d[0], d[1], d[2], d[3]);
        } else {
            for (int k = 0; k < 4; ++k) {
                const int j = j0 + k;
                if (j < S || j >= E) continue;
                float aa = 0.f, dd = 0.f;
#pragma unroll
                for (int t = 0; t < 8; ++t) {
                    const int idx = symfold(2 * j - 6 + t, NSRC);
                    const float v = src[SWZ(idx - BSRC)];
                    aa = fmaf(v, LO[t], aa);
                    dd = fmaf(v, HI[t], dd);
                }
                dstA[SWZ(j - BDST)] = aa;
                dstD[SWZ(j - BDST)] = dd;
            }
        }
    }
}

template<int S, int E, int BDST>
__device__ __forceinline__ void dwt_l1(const float* __restrict__ xr,
                                       float* __restrict__ dstA, int tid) {
    for (int j0 = (S & ~3) + tid * 4; j0 < E; j0 += NTHR * 4) {
        const int rb = 2 * j0 - 8;
        if ((rb >= 0) && (2 * j0 + 7 <= SIGLEN - 1) && (j0 + 4 <= E)) {
            const float4* s4 = reinterpret_cast<const float4*>(xr + rb);
            const float4 v0 = s4[0], v1 = s4[1], v2 = s4[2], v3 = s4[3];
            float w[16];
            w[0]=v0.x;  w[1]=v0.y;  w[2]=v0.z;  w[3]=v0.w;
            w[4]=v1.x;  w[5]=v1.y;  w[6]=v1.z;  w[7]=v1.w;
            w[8]=v2.x;  w[9]=v2.y;  w[10]=v2.z; w[11]=v2.w;
            w[12]=v3.x; w[13]=v3.y; w[14]=v3.z; w[15]=v3.w;
            float a[4];
#pragma unroll
            for (int k = 0; k < 4; ++k) {
                float aa = 0.f;
#pragma unroll
                for (int t = 0; t < 8; ++t) aa = fmaf(w[2 + 2 * k + t], LO[t], aa);
                a[k] = aa;
            }
            *reinterpret_cast<float4*>(dstA + SWZ(j0 - BDST)) = make_float4(a[0], a[1], a[2], a[3]);
        } else {
            for (int k = 0; k < 4; ++k) {
                const int j = j0 + k;
                if (j < S || j >= E) continue;
                float aa = 0.f;
#pragma unroll
                for (int t = 0; t < 8; ++t) {
                    const int idx = symfold(2 * j - 6 + t, SIGLEN);
                    aa = fmaf(xr[idx], LO[t], aa);
                }
                dstA[SWZ(j - BDST)] = aa;
            }
        }
    }
}

// Pool 64 owned buckets; lane 0 writes the mean as f16 (RTE -- no worse than the
// mlp's former cvt_pkrtz RTZ round-trip).
template<int N, int BASE, int P0>
__device__ __forceinline__ void pool64(const float* __restrict__ buf,
                                       __fp16* __restrict__ dst, int tid) {
    const int p = P0 + (tid >> 3), sub = tid & 7;
    const int s = (p * N) >> 7;
    const int e = ((p + 1) * N + 127) >> 7;
    float acc = 0.f;
    for (int t = s + sub; t < e; t += 8) acc += buf[SWZ(t - BASE)];
    acc += __shfl_xor(acc, 1);
    acc += __shfl_xor(acc, 2);
    acc += __shfl_xor(acc, 4);
    if (sub == 0) dst[p] = (__fp16)(acc / (float)(e - s));
}

template<int B>
__device__ __forceinline__ void dwt_body(const float* __restrict__ xr,
                                         __fp16* __restrict__ pr,
                                         float* __restrict__ A, float* __restrict__ Bb,
                                         float* __restrict__ D1, float* __restrict__ D2,
                                         int tid) {
    constexpr int p0 = B * 64;
    constexpr int sP5 = (p0 * N5) >> 7, eP5 = ((p0 + 64) * N5 + 127) >> 7;
    constexpr int sP4 = (p0 * N4) >> 7, eP4 = ((p0 + 64) * N4 + 127) >> 7;
    constexpr int sP3 = (p0 * N3) >> 7, eP3 = ((p0 + 64) * N3 + 127) >> 7;
    constexpr int sP2 = (p0 * N2) >> 7, eP2 = ((p0 + 64) * N2 + 127) >> 7;
    constexpr int s5 = sP5, e5 = cmin(eP5, N5);
    constexpr int s4 = cmax(cmin(sP4, 2 * s5 - 6), 0);
    constexpr int e4 = cmin(cmax(eP4, 2 * e5), N4);
    constexpr int s3 = cmax(cmin(sP3, 2 * s4 - 6), 0);
    constexpr int e3 = cmin(cmax(eP3, 2 * e4), N3);
    constexpr int s2 = cmax(cmin(sP2, 2 * s3 - 6), 0);
    constexpr int e2 = cmin(cmax(eP2, 2 * e3), N2);
    constexpr int s1 = cmax(2 * s2 - 6, 0);
    constexpr int e1 = cmin(2 * e2, N1);
    constexpr int b1 = (s1 & ~3) - 8, b2 = (s2 & ~3) - 8, b3 = (s3 & ~3) - 8;
    constexpr int b4 = (s4 & ~3) - 8, b5 = (s5 & ~3) - 8;

    dwt_l1<s1, e1, b1>(xr, A, tid);
    __syncthreads();
    dwt_chunk<s1, e1, b1, N1, s2, e2, b2>(A, Bb, D1, tid);
    __syncthreads();
    dwt_chunk<s2, e2, b2, N2, s3, e3, b3>(Bb, A, D2, tid);
    pool64<N2, b2, p0>(D1, pr + 4 * POOLP, tid);
    __syncthreads();
    dwt_chunk<s3, e3, b3, N3, s4, e4, b4>(A, Bb, D1, tid);
    pool64<N3, b3, p0>(D2, pr + 3 * POOLP, tid);
    __syncthreads();
    dwt_chunk<s4, e4, b4, N4, s5, e5, b5>(Bb, A, D2, tid);
    pool64<N4, b4, p0>(D1, pr + 2 * POOLP, tid);
    __syncthreads();
    pool64<N5, b5, p0>(A,  pr + 0 * POOLP, tid);
    pool64<N5, b5, p0>(D2, pr + 1 * POOLP, tid);
}

__global__ __launch_bounds__(NTHR, 4) void dwt_pool_kernel(const float* __restrict__ x,
                                                           __fp16* __restrict__ pooled) {
    __shared__ __align__(16) float A[4192];
    __shared__ __align__(16) float Bb[2144];
    __shared__ __align__(16) float D1[2144];
    __shared__ __align__(16) float D2[1088];
    const int tid = threadIdx.x;
    const int row = blockIdx.x >> 1;
    const float* __restrict__ xr = x + (size_t)row * SIGLEN;
    __fp16* __restrict__ pr = pooled + (size_t)row * COMB;
    if (blockIdx.x & 1) dwt_body<1>(xr, pr, A, Bb, D1, D2, tid);
    else                dwt_body<0>(xr, pr, A, Bb, D1, D2, tid);
}

// ---------------- MLP (r8 structure; reads f16 pooled directly) ----------------

#define LW_PAIRS (5 * 128 * 128 / 2)
#define FW_PAIRS (512 * 640 / 2)

__global__ __launch_bounds__(256) void pack_w(const float* __restrict__ lw,
                                              const float* __restrict__ fw,
                                              h2* __restrict__ lwh,
                                              h2* __restrict__ fwh) {
    const int i = blockIdx.x * 256 + threadIdx.x;
    if (i < LW_PAIRS) {
        const float2 v = reinterpret_cast<const float2*>(lw)[i];
        lwh[i] = __builtin_amdgcn_cvt_pkrtz(v.x, v.y);
    } else if (i < LW_PAIRS + FW_PAIRS) {
        const float2 v = reinterpret_cast<const float2*>(fw)[i - LW_PAIRS];
        fwh[i - LW_PAIRS] = __builtin_amdgcn_cvt_pkrtz(v.x, v.y);
    }
}

__global__ __launch_bounds__(1024, 4) void mlp_kernel(const __fp16* __restrict__ pooled,
                                                      const h2* __restrict__ lwh,
                                                      const float* __restrict__ lb,
                                                      const h2* __restrict__ fwh,
                                                      const float* __restrict__ fb,
                                                      float* __restrict__ out) {
    __shared__ h2 sph[8][COMB / 2];
    __shared__ h2 sch[8][COMB / 2];
    const int tid = threadIdx.x;
    const int r0 = blockIdx.x * 8;

    // pooled is already f16: plain dword copy (2560 dwords)
    const h2* __restrict__ srcp = reinterpret_cast<const h2*>(pooled + (size_t)r0 * COMB);
    for (int i = tid; i < 8 * (COMB / 2); i += 1024) {
        (&sph[0][0])[i] = srcp[i];
    }
    __syncthreads();

    for (int idx = tid; idx < COMB * 2; idx += 1024) {
        const int c = idx >> 1, rh = (idx & 1) * 4;
        const h2* __restrict__ w = lwh + (size_t)c * 64;
        const int lb2 = (c >> 7) * 64;
        const float bias = lb[c];
        float acc[4] = {bias, bias, bias, bias};
        for (int t2 = 0; t2 < 64; t2 += 4) {
            const float4 wraw = *reinterpret_cast<const float4*>(w + t2);
            const h2 w0 = __builtin_bit_cast(h2, wraw.x);
            const h2 w1 = __builtin_bit_cast(h2, wraw.y);
            const h2 w2 = __builtin_bit_cast(h2, wraw.z);
            const h2 w3 = __builtin_bit_cast(h2, wraw.w);
#pragma unroll
            for (int r = 0; r < 4; ++r) {
                const float4 praw = *reinterpret_cast<const float4*>(&sph[rh + r][lb2 + t2]);
                acc[r] = __builtin_amdgcn_fdot2(__builtin_bit_cast(h2, praw.x), w0, acc[r], false);
                acc[r] = __builtin_amdgcn_fdot2(__builtin_bit_cast(h2, praw.y), w1, acc[r], false);
                acc[r] = __builtin_amdgcn_fdot2(__builtin_bit_cast(h2, praw.z), w2, acc[r], false);
                acc[r] = __builtin_amdgcn_fdot2(__builtin_bit_cast(h2, praw.w), w3, acc[r], false);
            }
        }
        __fp16* __restrict__ schf = reinterpret_cast<__fp16*>(&sch[0][0]);
#pragma unroll
        for (int r = 0; r < 4; ++r) schf[(rh + r) * COMB + c] = (__fp16)fmaxf(acc[r], 0.f);
    }
    __syncthreads();

    {
        const int c = tid >> 1, rh = (tid & 1) * 4;
        const h2* __restrict__ w = fwh + (size_t)c * (COMB / 2);
        const float bias = fb[c];
        float acc[4] = {bias, bias, bias, bias};
        for (int t2 = 0; t2 < COMB / 2; t2 += 4) {
            const float4 wraw = *reinterpret_cast<const float4*>(w + t2);
            const h2 w0 = __builtin_bit_cast(h2, wraw.x);
            const h2 w1 = __builtin_bit_cast(h2, wraw.y);
            const h2 w2 = __builtin_bit_cast(h2, wraw.z);
            const h2 w3 = __builtin_bit_cast(h2, wraw.w);
#pragma unroll
            for (int r = 0; r < 4; ++r) {
                const float4 craw = *reinterpret_cast<const float4*>(&sch[rh + r][t2]);
                acc[r] = __builtin_amdgcn_fdot2(__builtin_bit_cast(h2, craw.x), w0, acc[r], false);
                acc[r] = __builtin_amdgcn_fdot2(__builtin_bit_cast(h2, craw.y), w1, acc[r], false);
                acc[r] = __builtin_amdgcn_fdot2(__builtin_bit_cast(h2, craw.z), w2, acc[r], false);
                acc[r] = __builtin_amdgcn_fdot2(__builtin_bit_cast(h2, craw.w), w3, acc[r], false);
            }
        }
#pragma unroll
        for (int r = 0; r < 4; ++r) {
            out[(size_t)(r0 + rh + r) * OUTD + c] = fmaxf(acc[r], 0.f);
        }
    }
}

// Fallback mlp: in-kernel weight cvt (used if d_ws lacks packed-weight space)
__global__ __launch_bounds__(512) void mlp_kernel_fb(const __fp16* __restrict__ pooled,
                                                     const float* __restrict__ lw,
                                                     const float* __restrict__ lb,
                                                     const float* __restrict__ fw,
                                                     const float* __restrict__ fb,
                                                     float* __restrict__ out) {
    __shared__ h2 sph[8][COMB / 2];
    __shared__ h2 sch[8][COMB / 2];
    const int tid = threadIdx.x;
    const int r0 = blockIdx.x * 8;
    const h2* __restrict__ srcp = reinterpret_cast<const h2*>(pooled + (size_t)r0 * COMB);
    for (int i = tid; i < 8 * (COMB / 2); i += 512) {
        (&sph[0][0])[i] = srcp[i];
    }
    __syncthreads();
    for (int c = tid; c < COMB; c += 512) {
        const float* __restrict__ w = lw + (size_t)c * POOLP;
        const int lb2 = (c >> 7) * (POOLP / 2);
        const float bias = lb[c];
        float acc[8];
#pragma unroll
        for (int r = 0; r < 8; ++r) acc[r] = bias;
        for (int t2 = 0; t2 < POOLP / 2; t2 += 4) {
            const float4 wa = *reinterpret_cast<const float4*>(w + t2 * 2);
            const float4 wb = *reinterpret_cast<const float4*>(w + t2 * 2 + 4);
            const h2 w0 = __builtin_amdgcn_cvt_pkrtz(wa.x, wa.y);
            const h2 w1 = __builtin_amdgcn_cvt_pkrtz(wa.z, wa.w);
            const h2 w2 = __builtin_amdgcn_cvt_pkrtz(wb.x, wb.y);
            const h2 w3 = __builtin_amdgcn_cvt_pkrtz(wb.z, wb.w);
#pragma unroll
            for (int r = 0; r < 8; ++r) {
                const float4 raw = *reinterpret_cast<const float4*>(&sph[r][lb2 + t2]);
                acc[r] = __builtin_amdgcn_fdot2(__builtin_bit_cast(h2, raw.x), w0, acc[r], false);
                acc[r] = __builtin_amdgcn_fdot2(__builtin_bit_cast(h2, raw.y), w1, acc[r], false);
                acc[r] = __builtin_amdgcn_fdot2(__builtin_bit_cast(h2, raw.z), w2, acc[r], false);
                acc[r] = __builtin_amdgcn_fdot2(__builtin_bit_cast(h2, raw.w), w3, acc[r], false);
            }
        }
        __fp16* __restrict__ schf = reinterpret_cast<__fp16*>(&sch[0][0]);
#pragma unroll
        for (int r = 0; r < 8; ++r) schf[r * COMB + c] = (__fp16)fmaxf(acc[r], 0.f);
    }
    __syncthreads();
    {
        const int j = tid;
        const float* __restrict__ w = fw + (size_t)j * COMB;
        const float bias = fb[j];
        float acc[8];
#pragma unroll
        for (int r = 0; r < 8; ++r) acc[r] = bias;
        for (int t2 = 0; t2 < COMB / 2; t2 += 4) {
            const float4 wa = *reinterpret_cast<const float4*>(w + t2 * 2);
            const float4 wb = *reinterpret_cast<const float4*>(w + t2 * 2 + 4);
            const h2 w0 = __builtin_amdgcn_cvt_pkrtz(wa.x, wa.y);
            const h2 w1 = __builtin_amdgcn_cvt_pkrtz(wa.z, wa.w);
            const h2 w2 = __builtin_amdgcn_cvt_pkrtz(wb.x, wb.y);
            const h2 w3 = __builtin_amdgcn_cvt_pkrtz(wb.z, wb.w);
#pragma unroll
            for (int r = 0; r < 8; ++r) {
                const float4 raw = *reinterpret_cast<const float4*>(&sch[r][t2]);
                acc[r] = __builtin_amdgcn_fdot2(__builtin_bit_cast(h2, raw.x), w0, acc[r], false);
                acc[r] = __builtin_amdgcn_fdot2(__builtin_bit_cast(h2, raw.y), w1, acc[r], false);
                acc[r] = __builtin_amdgcn_fdot2(__builtin_bit_cast(h2, raw.z), w2, acc[r], false);
                acc[r] = __builtin_amdgcn_fdot2(__builtin_bit_cast(h2, raw.w), w3, acc[r], false);
            }
        }
#pragma unroll
        for (int r = 0; r < 8; ++r) {
            out[(size_t)(r0 + r) * OUTD + j] = fmaxf(acc[r], 0.f);
        }
    }
}

extern "C" void kernel_launch(void* const* d_in, const int* in_sizes, int n_in,
                              void* d_out, int out_size, void* d_ws, size_t ws_size,
                              hipStream_t stream) {
    const float* x  = (const float*)d_in[0];
    const float* lw = (const float*)d_in[1];
    const float* lb = (const float*)d_in[2];
    const float* fw = (const float*)d_in[3];
    const float* fb = (const float*)d_in[4];
    float* out = (float*)d_out;

    char* base = (char*)d_ws;
    const size_t POOLED_B = (size_t)BATCH * COMB * 2;            // f16, 2,621,440
    const size_t LWH_B    = (size_t)LW_PAIRS * 4;                // 163,840
    const size_t FWH_B    = (size_t)FW_PAIRS * 4;                // 655,360

    __fp16* pooled = (__fp16*)base;
    h2* lwh = (h2*)(base + POOLED_B);
    h2* fwh = (h2*)(base + POOLED_B + LWH_B);

    const size_t NEED_MLP = POOLED_B + LWH_B + FWH_B;

    dwt_pool_kernel<<<BATCH * 2, NTHR, 0, stream>>>(x, pooled);

    if (ws_size >= NEED_MLP) {
        pack_w<<<(LW_PAIRS + FW_PAIRS + 255) / 256, 256, 0, stream>>>(lw, fw, lwh, fwh);
        mlp_kernel<<<BATCH / 8, 1024, 0, stream>>>(pooled, lwh, lb, fwh, fb, out);
    } else {
        mlp_kernel_fb<<<BATCH / 8, 512, 0, stream>>>(pooled, lw, lb, fw, fb, out);
    }
}

// Round 19
// 89.005 us; speedup vs baseline: 4.1753x; 1.0104x over previous
//
#include <hip/hip_runtime.h>

// WaveletFeatureExtractor: db4 wavedec (5 levels, symmetric pad) -> adaptive pool 128
// -> per-level 128x128 MLP (ReLU) -> fused 640->512 MLP (ReLU).
//
// Round 19 = round 18 (champion: cascade dwt 77us + f16 pooled + f16-dot2 mlp)
// with the dwt inner loops rewritten in packed f32 (v_pk_fma_f32 via <2 x float>
// vector arithmetic -- IEEE f32, zero precision change):
//  - L2..L5: (cA,cD) pair packed: 16 scalar FMA -> 8 packed per output.
//  - L1 (LO-only): output pairs packed: 32 -> 16 packed per 4-output group.
// dwt is VALU-issue-bound (50% busy at the 32-wave/CU occupancy cap), FMA ~2/3
// of the stream -> predicted ~1/3 issue cut.

#define BATCH   2048
#define SIGLEN  16384
#define N1      8195
#define N2      4101
#define N3      2054
#define N4      1030
#define N5      518
#define POOLP   128
#define COMB    640
#define OUTD    512
#define NTHR    512

#define SWZ(i) ((i) ^ ((((i) >> 5) & 7) << 2))

typedef __fp16 h2 __attribute__((ext_vector_type(2)));
typedef float  f2 __attribute__((ext_vector_type(2)));

__device__ constexpr float LO[8] = {
     0.2303778133088965f,   0.7148465705529157f,   0.6308807679298589f,
    -0.027983769416859854f, -0.18703481171909309f,  0.030841381835560764f,
     0.0328830116668852f,  -0.010597401785069032f };
__device__ constexpr float HI[8] = {
    -0.010597401785069032f, -0.0328830116668852f,   0.030841381835560764f,
     0.18703481171909309f,  -0.027983769416859854f, -0.6308807679298589f,
     0.7148465705529157f,  -0.2303778133088965f };

__device__ __forceinline__ int symfold(int idx, int n) {
    idx = (idx < 0) ? (-1 - idx) : idx;
    idx = (idx >= n) ? (2 * n - 1 - idx) : idx;
    return idx;
}
constexpr int cmin(int a, int b) { return a < b ? a : b; }
constexpr int cmax(int a, int b) { return a > b ? a : b; }

template<int SS, int SE, int BSRC, int NSRC, int S, int E, int BDST>
__device__ __forceinline__ void dwt_chunk(const float* __restrict__ src,
                                          float* __restrict__ dstA,
                                          float* __restrict__ dstD, int tid) {
    for (int j0 = (S & ~3) + tid * 4; j0 < E; j0 += NTHR * 4) {
        const int rb = 2 * j0 - 8;
        if ((rb >= SS) && (2 * j0 + 7 <= SE - 1) && (j0 + 4 <= E)) {
            const int lrb = rb - BSRC;
            const float4 v0 = *reinterpret_cast<const float4*>(src + SWZ(lrb));
            const float4 v1 = *reinterpret_cast<const float4*>(src + SWZ(lrb + 4));
            const float4 v2 = *reinterpret_cast<const float4*>(src + SWZ(lrb + 8));
            const float4 v3 = *reinterpret_cast<const float4*>(src + SWZ(lrb + 12));
            float w[16];
            w[0]=v0.x;  w[1]=v0.y;  w[2]=v0.z;  w[3]=v0.w;
            w[4]=v1.x;  w[5]=v1.y;  w[6]=v1.z;  w[7]=v1.w;
            w[8]=v2.x;  w[9]=v2.y;  w[10]=v2.z; w[11]=v2.w;
            w[12]=v3.x; w[13]=v3.y; w[14]=v3.z; w[15]=v3.w;
            float a[4], d[4];
#pragma unroll
            for (int k = 0; k < 4; ++k) {
                // packed (cA,cD): one v_pk_fma_f32 per tap
                f2 ad = {0.f, 0.f};
#pragma unroll
                for (int t = 0; t < 8; ++t) {
                    const float v = w[2 + 2 * k + t];
                    const f2 vv = {v, v};
                    const f2 lh = {LO[t], HI[t]};
                    ad = vv * lh + ad;
                }
                a[k] = ad.x; d[k] = ad.y;
            }
            const int ds = j0 - BDST;
            *reinterpret_cast<float4*>(dstA + SWZ(ds)) = make_float4(a[0], a[1], a[2], a[3]);
            *reinterpret_cast<float4*>(dstD + SWZ(ds)) = make_float4(d[0], d[1], d[2], d[3]);
        } else {
            for (int k = 0; k < 4; ++k) {
                const int j = j0 + k;
                if (j < S || j >= E) continue;
                float aa = 0.f, dd = 0.f;
#pragma unroll
                for (int t = 0; t < 8; ++t) {
                    const int idx = symfold(2 * j - 6 + t, NSRC);
                    const float v = src[SWZ(idx - BSRC)];
                    aa = fmaf(v, LO[t], aa);
                    dd = fmaf(v, HI[t], dd);
                }
                dstA[SWZ(j - BDST)] = aa;
                dstD[SWZ(j - BDST)] = dd;
            }
        }
    }
}

template<int S, int E, int BDST>
__device__ __forceinline__ void dwt_l1(const float* __restrict__ xr,
                                       float* __restrict__ dstA, int tid) {
    for (int j0 = (S & ~3) + tid * 4; j0 < E; j0 += NTHR * 4) {
        const int rb = 2 * j0 - 8;
        if ((rb >= 0) && (2 * j0 + 7 <= SIGLEN - 1) && (j0 + 4 <= E)) {
            const float4* s4 = reinterpret_cast<const float4*>(xr + rb);
            const float4 v0 = s4[0], v1 = s4[1], v2 = s4[2], v3 = s4[3];
            float w[16];
            w[0]=v0.x;  w[1]=v0.y;  w[2]=v0.z;  w[3]=v0.w;
            w[4]=v1.x;  w[5]=v1.y;  w[6]=v1.z;  w[7]=v1.w;
            w[8]=v2.x;  w[9]=v2.y;  w[10]=v2.z; w[11]=v2.w;
            w[12]=v3.x; w[13]=v3.y; w[14]=v3.z; w[15]=v3.w;
            // packed output pairs (out0,out1) and (out2,out3)
            f2 a01 = {0.f, 0.f}, a23 = {0.f, 0.f};
#pragma unroll
            for (int t = 0; t < 8; ++t) {
                const f2 p01 = {w[2 + t], w[4 + t]};
                const f2 p23 = {w[6 + t], w[8 + t]};
                a01 = p01 * LO[t] + a01;
                a23 = p23 * LO[t] + a23;
            }
            *reinterpret_cast<float4*>(dstA + SWZ(j0 - BDST)) =
                make_float4(a01.x, a01.y, a23.x, a23.y);
        } else {
            for (int k = 0; k < 4; ++k) {
                const int j = j0 + k;
                if (j < S || j >= E) continue;
                float aa = 0.f;
#pragma unroll
                for (int t = 0; t < 8; ++t) {
                    const int idx = symfold(2 * j - 6 + t, SIGLEN);
                    aa = fmaf(xr[idx], LO[t], aa);
                }
                dstA[SWZ(j - BDST)] = aa;
            }
        }
    }
}

// Pool 64 owned buckets; lane 0 writes the mean as f16 (RTE).
template<int N, int BASE, int P0>
__device__ __forceinline__ void pool64(const float* __restrict__ buf,
                                       __fp16* __restrict__ dst, int tid) {
    const int p = P0 + (tid >> 3), sub = tid & 7;
    const int s = (p * N) >> 7;
    const int e = ((p + 1) * N + 127) >> 7;
    float acc = 0.f;
    for (int t = s + sub; t < e; t += 8) acc += buf[SWZ(t - BASE)];
    acc += __shfl_xor(acc, 1);
    acc += __shfl_xor(acc, 2);
    acc += __shfl_xor(acc, 4);
    if (sub == 0) dst[p] = (__fp16)(acc / (float)(e - s));
}

template<int B>
__device__ __forceinline__ void dwt_body(const float* __restrict__ xr,
                                         __fp16* __restrict__ pr,
                                         float* __restrict__ A, float* __restrict__ Bb,
                                         float* __restrict__ D1, float* __restrict__ D2,
                                         int tid) {
    constexpr int p0 = B * 64;
    constexpr int sP5 = (p0 * N5) >> 7, eP5 = ((p0 + 64) * N5 + 127) >> 7;
    constexpr int sP4 = (p0 * N4) >> 7, eP4 = ((p0 + 64) * N4 + 127) >> 7;
    constexpr int sP3 = (p0 * N3) >> 7, eP3 = ((p0 + 64) * N3 + 127) >> 7;
    constexpr int sP2 = (p0 * N2) >> 7, eP2 = ((p0 + 64) * N2 + 127) >> 7;
    constexpr int s5 = sP5, e5 = cmin(eP5, N5);
    constexpr int s4 = cmax(cmin(sP4, 2 * s5 - 6), 0);
    constexpr int e4 = cmin(cmax(eP4, 2 * e5), N4);
    constexpr int s3 = cmax(cmin(sP3, 2 * s4 - 6), 0);
    constexpr int e3 = cmin(cmax(eP3, 2 * e4), N3);
    constexpr int s2 = cmax(cmin(sP2, 2 * s3 - 6), 0);
    constexpr int e2 = cmin(cmax(eP2, 2 * e3), N2);
    constexpr int s1 = cmax(2 * s2 - 6, 0);
    constexpr int e1 = cmin(2 * e2, N1);
    constexpr int b1 = (s1 & ~3) - 8, b2 = (s2 & ~3) - 8, b3 = (s3 & ~3) - 8;
    constexpr int b4 = (s4 & ~3) - 8, b5 = (s5 & ~3) - 8;

    dwt_l1<s1, e1, b1>(xr, A, tid);
    __syncthreads();
    dwt_chunk<s1, e1, b1, N1, s2, e2, b2>(A, Bb, D1, tid);
    __syncthreads();
    dwt_chunk<s2, e2, b2, N2, s3, e3, b3>(Bb, A, D2, tid);
    pool64<N2, b2, p0>(D1, pr + 4 * POOLP, tid);
    __syncthreads();
    dwt_chunk<s3, e3, b3, N3, s4, e4, b4>(A, Bb, D1, tid);
    pool64<N3, b3, p0>(D2, pr + 3 * POOLP, tid);
    __syncthreads();
    dwt_chunk<s4, e4, b4, N4, s5, e5, b5>(Bb, A, D2, tid);
    pool64<N4, b4, p0>(D1, pr + 2 * POOLP, tid);
    __syncthreads();
    pool64<N5, b5, p0>(A,  pr + 0 * POOLP, tid);
    pool64<N5, b5, p0>(D2, pr + 1 * POOLP, tid);
}

__global__ __launch_bounds__(NTHR, 4) void dwt_pool_kernel(const float* __restrict__ x,
                                                           __fp16* __restrict__ pooled) {
    __shared__ __align__(16) float A[4192];
    __shared__ __align__(16) float Bb[2144];
    __shared__ __align__(16) float D1[2144];
    __shared__ __align__(16) float D2[1088];
    const int tid = threadIdx.x;
    const int row = blockIdx.x >> 1;
    const float* __restrict__ xr = x + (size_t)row * SIGLEN;
    __fp16* __restrict__ pr = pooled + (size_t)row * COMB;
    if (blockIdx.x & 1) dwt_body<1>(xr, pr, A, Bb, D1, D2, tid);
    else                dwt_body<0>(xr, pr, A, Bb, D1, D2, tid);
}

// ---------------- MLP (r18: f16 pooled input, pre-packed f16 weights) ----------------

#define LW_PAIRS (5 * 128 * 128 / 2)
#define FW_PAIRS (512 * 640 / 2)

__global__ __launch_bounds__(256) void pack_w(const float* __restrict__ lw,
                                              const float* __restrict__ fw,
                                              h2* __restrict__ lwh,
                                              h2* __restrict__ fwh) {
    const int i = blockIdx.x * 256 + threadIdx.x;
    if (i < LW_PAIRS) {
        const float2 v = reinterpret_cast<const float2*>(lw)[i];
        lwh[i] = __builtin_amdgcn_cvt_pkrtz(v.x, v.y);
    } else if (i < LW_PAIRS + FW_PAIRS) {
        const float2 v = reinterpret_cast<const float2*>(fw)[i - LW_PAIRS];
        fwh[i - LW_PAIRS] = __builtin_amdgcn_cvt_pkrtz(v.x, v.y);
    }
}

__global__ __launch_bounds__(1024, 4) void mlp_kernel(const __fp16* __restrict__ pooled,
                                                      const h2* __restrict__ lwh,
                                                      const float* __restrict__ lb,
                                                      const h2* __restrict__ fwh,
                                                      const float* __restrict__ fb,
                                                      float* __restrict__ out) {
    __shared__ h2 sph[8][COMB / 2];
    __shared__ h2 sch[8][COMB / 2];
    const int tid = threadIdx.x;
    const int r0 = blockIdx.x * 8;

    const h2* __restrict__ srcp = reinterpret_cast<const h2*>(pooled + (size_t)r0 * COMB);
    for (int i = tid; i < 8 * (COMB / 2); i += 1024) {
        (&sph[0][0])[i] = srcp[i];
    }
    __syncthreads();

    for (int idx = tid; idx < COMB * 2; idx += 1024) {
        const int c = idx >> 1, rh = (idx & 1) * 4;
        const h2* __restrict__ w = lwh + (size_t)c * 64;
        const int lb2 = (c >> 7) * 64;
        const float bias = lb[c];
        float acc[4] = {bias, bias, bias, bias};
        for (int t2 = 0; t2 < 64; t2 += 4) {
            const float4 wraw = *reinterpret_cast<const float4*>(w + t2);
            const h2 w0 = __builtin_bit_cast(h2, wraw.x);
            const h2 w1 = __builtin_bit_cast(h2, wraw.y);
            const h2 w2 = __builtin_bit_cast(h2, wraw.z);
            const h2 w3 = __builtin_bit_cast(h2, wraw.w);
#pragma unroll
            for (int r = 0; r < 4; ++r) {
                const float4 praw = *reinterpret_cast<const float4*>(&sph[rh + r][lb2 + t2]);
                acc[r] = __builtin_amdgcn_fdot2(__builtin_bit_cast(h2, praw.x), w0, acc[r], false);
                acc[r] = __builtin_amdgcn_fdot2(__builtin_bit_cast(h2, praw.y), w1, acc[r], false);
                acc[r] = __builtin_amdgcn_fdot2(__builtin_bit_cast(h2, praw.z), w2, acc[r], false);
                acc[r] = __builtin_amdgcn_fdot2(__builtin_bit_cast(h2, praw.w), w3, acc[r], false);
            }
        }
        __fp16* __restrict__ schf = reinterpret_cast<__fp16*>(&sch[0][0]);
#pragma unroll
        for (int r = 0; r < 4; ++r) schf[(rh + r) * COMB + c] = (__fp16)fmaxf(acc[r], 0.f);
    }
    __syncthreads();

    {
        const int c = tid >> 1, rh = (tid & 1) * 4;
        const h2* __restrict__ w = fwh + (size_t)c * (COMB / 2);
        const float bias = fb[c];
        float acc[4] = {bias, bias, bias, bias};
        for (int t2 = 0; t2 < COMB / 2; t2 += 4) {
            const float4 wraw = *reinterpret_cast<const float4*>(w + t2);
            const h2 w0 = __builtin_bit_cast(h2, wraw.x);
            const h2 w1 = __builtin_bit_cast(h2, wraw.y);
            const h2 w2 = __builtin_bit_cast(h2, wraw.z);
            const h2 w3 = __builtin_bit_cast(h2, wraw.w);
#pragma unroll
            for (int r = 0; r < 4; ++r) {
                const float4 craw = *reinterpret_cast<const float4*>(&sch[rh + r][t2]);
                acc[r] = __builtin_amdgcn_fdot2(__builtin_bit_cast(h2, craw.x), w0, acc[r], false);
                acc[r] = __builtin_amdgcn_fdot2(__builtin_bit_cast(h2, craw.y), w1, acc[r], false);
                acc[r] = __builtin_amdgcn_fdot2(__builtin_bit_cast(h2, craw.z), w2, acc[r], false);
                acc[r] = __builtin_amdgcn_fdot2(__builtin_bit_cast(h2, craw.w), w3, acc[r], false);
            }
        }
#pragma unroll
        for (int r = 0; r < 4; ++r) {
            out[(size_t)(r0 + rh + r) * OUTD + c] = fmaxf(acc[r], 0.f);
        }
    }
}

// Fallback mlp: in-kernel weight cvt (used if d_ws lacks packed-weight space)
__global__ __launch_bounds__(512) void mlp_kernel_fb(const __fp16* __restrict__ pooled,
                                                     const float* __restrict__ lw,
                                                     const float* __restrict__ lb,
                                                     const float* __restrict__ fw,
                                                     const float* __restrict__ fb,
                                                     float* __restrict__ out) {
    __shared__ h2 sph[8][COMB / 2];
    __shared__ h2 sch[8][COMB / 2];
    const int tid = threadIdx.x;
    const int r0 = blockIdx.x * 8;
    const h2* __restrict__ srcp = reinterpret_cast<const h2*>(pooled + (size_t)r0 * COMB);
    for (int i = tid; i < 8 * (COMB / 2); i += 512) {
        (&sph[0][0])[i] = srcp[i];
    }
    __syncthreads();
    for (int c = tid; c < COMB; c += 512) {
        const float* __restrict__ w = lw + (size_t)c * POOLP;
        const int lb2 = (c >> 7) * (POOLP / 2);
        const float bias = lb[c];
        float acc[8];
#pragma unroll
        for (int r = 0; r < 8; ++r) acc[r] = bias;
        for (int t2 = 0; t2 < POOLP / 2; t2 += 4) {
            const float4 wa = *reinterpret_cast<const float4*>(w + t2 * 2);
            const float4 wb = *reinterpret_cast<const float4*>(w + t2 * 2 + 4);
            const h2 w0 = __builtin_amdgcn_cvt_pkrtz(wa.x, wa.y);
            const h2 w1 = __builtin_amdgcn_cvt_pkrtz(wa.z, wa.w);
            const h2 w2 = __builtin_amdgcn_cvt_pkrtz(wb.x, wb.y);
            const h2 w3 = __builtin_amdgcn_cvt_pkrtz(wb.z, wb.w);
#pragma unroll
            for (int r = 0; r < 8; ++r) {
                const float4 raw = *reinterpret_cast<const float4*>(&sph[r][lb2 + t2]);
                acc[r] = __builtin_amdgcn_fdot2(__builtin_bit_cast(h2, raw.x), w0, acc[r], false);
                acc[r] = __builtin_amdgcn_fdot2(__builtin_bit_cast(h2, raw.y), w1, acc[r], false);
                acc[r] = __builtin_amdgcn_fdot2(__builtin_bit_cast(h2, raw.z), w2, acc[r], false);
                acc[r] = __builtin_amdgcn_fdot2(__builtin_bit_cast(h2, raw.w), w3, acc[r], false);
            }
        }
        __fp16* __restrict__ schf = reinterpret_cast<__fp16*>(&sch[0][0]);
#pragma unroll
        for (int r = 0; r < 8; ++r) schf[r * COMB + c] = (__fp16)fmaxf(acc[r], 0.f);
    }
    __syncthreads();
    {
        const int j = tid;
        const float* __restrict__ w = fw + (size_t)j * COMB;
        const float bias = fb[j];
        float acc[8];
#pragma unroll
        for (int r = 0; r < 8; ++r) acc[r] = bias;
        for (int t2 = 0; t2 < COMB / 2; t2 += 4) {
            const float4 wa = *reinterpret_cast<const float4*>(w + t2 * 2);
            const float4 wb = *reinterpret_cast<const float4*>(w + t2 * 2 + 4);
            const h2 w0 = __builtin_amdgcn_cvt_pkrtz(wa.x, wa.y);
            const h2 w1 = __builtin_amdgcn_cvt_pkrtz(wa.z, wa.w);
            const h2 w2 = __builtin_amdgcn_cvt_pkrtz(wb.x, wb.y);
            const h2 w3 = __builtin_amdgcn_cvt_pkrtz(wb.z, wb.w);
#pragma unroll
            for (int r = 0; r < 8; ++r) {
                const float4 raw = *reinterpret_cast<const float4*>(&sch[r][t2]);
                acc[r] = __builtin_amdgcn_fdot2(__builtin_bit_cast(h2, raw.x), w0, acc[r], false);
                acc[r] = __builtin_amdgcn_fdot2(__builtin_bit_cast(h2, raw.y), w1, acc[r], false);
                acc[r] = __builtin_amdgcn_fdot2(__builtin_bit_cast(h2, raw.z), w2, acc[r], false);
                acc[r] = __builtin_amdgcn_fdot2(__builtin_bit_cast(h2, raw.w), w3, acc[r], false);
            }
        }
#pragma unroll
        for (int r = 0; r < 8; ++r) {
            out[(size_t)(r0 + r) * OUTD + j] = fmaxf(acc[r], 0.f);
        }
    }
}

extern "C" void kernel_launch(void* const* d_in, const int* in_sizes, int n_in,
                              void* d_out, int out_size, void* d_ws, size_t ws_size,
                              hipStream_t stream) {
    const float* x  = (const float*)d_in[0];
    const float* lw = (const float*)d_in[1];
    const float* lb = (const float*)d_in[2];
    const float* fw = (const float*)d_in[3];
    const float* fb = (const float*)d_in[4];
    float* out = (float*)d_out;

    char* base = (char*)d_ws;
    const size_t POOLED_B = (size_t)BATCH * COMB * 2;            // f16, 2,621,440
    const size_t LWH_B    = (size_t)LW_PAIRS * 4;                // 163,840
    const size_t FWH_B    = (size_t)FW_PAIRS * 4;                // 655,360

    __fp16* pooled = (__fp16*)base;
    h2* lwh = (h2*)(base + POOLED_B);
    h2* fwh = (h2*)(base + POOLED_B + LWH_B);

    const size_t NEED_MLP = POOLED_B + LWH_B + FWH_B;

    dwt_pool_kernel<<<BATCH * 2, NTHR, 0, stream>>>(x, pooled);

    if (ws_size >= NEED_MLP) {
        pack_w<<<(LW_PAIRS + FW_PAIRS + 255) / 256, 256, 0, stream>>>(lw, fw, lwh, fwh);
        mlp_kernel<<<BATCH / 8, 1024, 0, stream>>>(pooled, lwh, lb, fwh, fb, out);
    } else {
        mlp_kernel_fb<<<BATCH / 8, 512, 0, stream>>>(pooled, lw, lb, fw, fb, out);
    }
}

// Round 20
// 87.983 us; speedup vs baseline: 4.2238x; 1.0116x over previous
//
#include <hip/hip_runtime.h>

// WaveletFeatureExtractor: db4 wavedec (5 levels, symmetric pad) -> adaptive pool 128
// -> per-level 128x128 MLP (ReLU) -> fused 640->512 MLP (ReLU).
//
// Round 20 = r19 champion (cascade dwt + f16 pooled + f16-dot2 mlp) with:
//  1. __builtin_elementwise_fma on the <2 x float> accumulators -> guaranteed
//     llvm.fma.v2f32 -> v_pk_fma_f32 (r19's plain mul+add may have scalarized:
//     wall+VALUBusy both flat; this disambiguates issue-bound vs latency-bound).
//  2. pack_w folded into dwt_pool (first 800 blocks convert 256 weight pairs
//     each at kernel entry -- no dependency, removes one serialized launch).

#define BATCH   2048
#define SIGLEN  16384
#define N1      8195
#define N2      4101
#define N3      2054
#define N4      1030
#define N5      518
#define POOLP   128
#define COMB    640
#define OUTD    512
#define NTHR    512

#define LW_PAIRS (5 * 128 * 128 / 2)   // 40960
#define FW_PAIRS (512 * 640 / 2)       // 163840
#define PACK_BLOCKS ((LW_PAIRS + FW_PAIRS) / 256)  // 800

#define SWZ(i) ((i) ^ ((((i) >> 5) & 7) << 2))

typedef __fp16 h2 __attribute__((ext_vector_type(2)));
typedef float  f2 __attribute__((ext_vector_type(2)));

__device__ constexpr float LO[8] = {
     0.2303778133088965f,   0.7148465705529157f,   0.6308807679298589f,
    -0.027983769416859854f, -0.18703481171909309f,  0.030841381835560764f,
     0.0328830116668852f,  -0.010597401785069032f };
__device__ constexpr float HI[8] = {
    -0.010597401785069032f, -0.0328830116668852f,   0.030841381835560764f,
     0.18703481171909309f,  -0.027983769416859854f, -0.6308807679298589f,
     0.7148465705529157f,  -0.2303778133088965f };

__device__ __forceinline__ int symfold(int idx, int n) {
    idx = (idx < 0) ? (-1 - idx) : idx;
    idx = (idx >= n) ? (2 * n - 1 - idx) : idx;
    return idx;
}
constexpr int cmin(int a, int b) { return a < b ? a : b; }
constexpr int cmax(int a, int b) { return a > b ? a : b; }

template<int SS, int SE, int BSRC, int NSRC, int S, int E, int BDST>
__device__ __forceinline__ void dwt_chunk(const float* __restrict__ src,
                                          float* __restrict__ dstA,
                                          float* __restrict__ dstD, int tid) {
    for (int j0 = (S & ~3) + tid * 4; j0 < E; j0 += NTHR * 4) {
        const int rb = 2 * j0 - 8;
        if ((rb >= SS) && (2 * j0 + 7 <= SE - 1) && (j0 + 4 <= E)) {
            const int lrb = rb - BSRC;
            const float4 v0 = *reinterpret_cast<const float4*>(src + SWZ(lrb));
            const float4 v1 = *reinterpret_cast<const float4*>(src + SWZ(lrb + 4));
            const float4 v2 = *reinterpret_cast<const float4*>(src + SWZ(lrb + 8));
            const float4 v3 = *reinterpret_cast<const float4*>(src + SWZ(lrb + 12));
            float w[16];
            w[0]=v0.x;  w[1]=v0.y;  w[2]=v0.z;  w[3]=v0.w;
            w[4]=v1.x;  w[5]=v1.y;  w[6]=v1.z;  w[7]=v1.w;
            w[8]=v2.x;  w[9]=v2.y;  w[10]=v2.z; w[11]=v2.w;
            w[12]=v3.x; w[13]=v3.y; w[14]=v3.z; w[15]=v3.w;
            float a[4], d[4];
#pragma unroll
            for (int k = 0; k < 4; ++k) {
                f2 ad = {0.f, 0.f};
#pragma unroll
                for (int t = 0; t < 8; ++t) {
                    const float v = w[2 + 2 * k + t];
                    const f2 vv = {v, v};
                    const f2 lh = {LO[t], HI[t]};
                    ad = __builtin_elementwise_fma(vv, lh, ad);   // v_pk_fma_f32
                }
                a[k] = ad.x; d[k] = ad.y;
            }
            const int ds = j0 - BDST;
            *reinterpret_cast<float4*>(dstA + SWZ(ds)) = make_float4(a[0], a[1], a[2], a[3]);
            *reinterpret_cast<float4*>(dstD + SWZ(ds)) = make_float4(d[0], d[1], d[2], d[3]);
        } else {
            for (int k = 0; k < 4; ++k) {
                const int j = j0 + k;
                if (j < S || j >= E) continue;
                float aa = 0.f, dd = 0.f;
#pragma unroll
                for (int t = 0; t < 8; ++t) {
                    const int idx = symfold(2 * j - 6 + t, NSRC);
                    const float v = src[SWZ(idx - BSRC)];
                    aa = fmaf(v, LO[t], aa);
                    dd = fmaf(v, HI[t], dd);
                }
                dstA[SWZ(j - BDST)] = aa;
                dstD[SWZ(j - BDST)] = dd;
            }
        }
    }
}

template<int S, int E, int BDST>
__device__ __forceinline__ void dwt_l1(const float* __restrict__ xr,
                                       float* __restrict__ dstA, int tid) {
    for (int j0 = (S & ~3) + tid * 4; j0 < E; j0 += NTHR * 4) {
        const int rb = 2 * j0 - 8;
        if ((rb >= 0) && (2 * j0 + 7 <= SIGLEN - 1) && (j0 + 4 <= E)) {
            const float4* s4 = reinterpret_cast<const float4*>(xr + rb);
            const float4 v0 = s4[0], v1 = s4[1], v2 = s4[2], v3 = s4[3];
            float w[16];
            w[0]=v0.x;  w[1]=v0.y;  w[2]=v0.z;  w[3]=v0.w;
            w[4]=v1.x;  w[5]=v1.y;  w[6]=v1.z;  w[7]=v1.w;
            w[8]=v2.x;  w[9]=v2.y;  w[10]=v2.z; w[11]=v2.w;
            w[12]=v3.x; w[13]=v3.y; w[14]=v3.z; w[15]=v3.w;
            f2 a01 = {0.f, 0.f}, a23 = {0.f, 0.f};
#pragma unroll
            for (int t = 0; t < 8; ++t) {
                const f2 p01 = {w[2 + t], w[4 + t]};
                const f2 p23 = {w[6 + t], w[8 + t]};
                const f2 lt  = {LO[t], LO[t]};
                a01 = __builtin_elementwise_fma(p01, lt, a01);
                a23 = __builtin_elementwise_fma(p23, lt, a23);
            }
            *reinterpret_cast<float4*>(dstA + SWZ(j0 - BDST)) =
                make_float4(a01.x, a01.y, a23.x, a23.y);
        } else {
            for (int k = 0; k < 4; ++k) {
                const int j = j0 + k;
                if (j < S || j >= E) continue;
                float aa = 0.f;
#pragma unroll
                for (int t = 0; t < 8; ++t) {
                    const int idx = symfold(2 * j - 6 + t, SIGLEN);
                    aa = fmaf(xr[idx], LO[t], aa);
                }
                dstA[SWZ(j - BDST)] = aa;
            }
        }
    }
}

// Pool 64 owned buckets; lane 0 writes the mean as f16 (RTE).
template<int N, int BASE, int P0>
__device__ __forceinline__ void pool64(const float* __restrict__ buf,
                                       __fp16* __restrict__ dst, int tid) {
    const int p = P0 + (tid >> 3), sub = tid & 7;
    const int s = (p * N) >> 7;
    const int e = ((p + 1) * N + 127) >> 7;
    float acc = 0.f;
    for (int t = s + sub; t < e; t += 8) acc += buf[SWZ(t - BASE)];
    acc += __shfl_xor(acc, 1);
    acc += __shfl_xor(acc, 2);
    acc += __shfl_xor(acc, 4);
    if (sub == 0) dst[p] = (__fp16)(acc / (float)(e - s));
}

template<int B>
__device__ __forceinline__ void dwt_body(const float* __restrict__ xr,
                                         __fp16* __restrict__ pr,
                                         float* __restrict__ A, float* __restrict__ Bb,
                                         float* __restrict__ D1, float* __restrict__ D2,
                                         int tid) {
    constexpr int p0 = B * 64;
    constexpr int sP5 = (p0 * N5) >> 7, eP5 = ((p0 + 64) * N5 + 127) >> 7;
    constexpr int sP4 = (p0 * N4) >> 7, eP4 = ((p0 + 64) * N4 + 127) >> 7;
    constexpr int sP3 = (p0 * N3) >> 7, eP3 = ((p0 + 64) * N3 + 127) >> 7;
    constexpr int sP2 = (p0 * N2) >> 7, eP2 = ((p0 + 64) * N2 + 127) >> 7;
    constexpr int s5 = sP5, e5 = cmin(eP5, N5);
    constexpr int s4 = cmax(cmin(sP4, 2 * s5 - 6), 0);
    constexpr int e4 = cmin(cmax(eP4, 2 * e5), N4);
    constexpr int s3 = cmax(cmin(sP3, 2 * s4 - 6), 0);
    constexpr int e3 = cmin(cmax(eP3, 2 * e4), N3);
    constexpr int s2 = cmax(cmin(sP2, 2 * s3 - 6), 0);
    constexpr int e2 = cmin(cmax(eP2, 2 * e3), N2);
    constexpr int s1 = cmax(2 * s2 - 6, 0);
    constexpr int e1 = cmin(2 * e2, N1);
    constexpr int b1 = (s1 & ~3) - 8, b2 = (s2 & ~3) - 8, b3 = (s3 & ~3) - 8;
    constexpr int b4 = (s4 & ~3) - 8, b5 = (s5 & ~3) - 8;

    dwt_l1<s1, e1, b1>(xr, A, tid);
    __syncthreads();
    dwt_chunk<s1, e1, b1, N1, s2, e2, b2>(A, Bb, D1, tid);
    __syncthreads();
    dwt_chunk<s2, e2, b2, N2, s3, e3, b3>(Bb, A, D2, tid);
    pool64<N2, b2, p0>(D1, pr + 4 * POOLP, tid);
    __syncthreads();
    dwt_chunk<s3, e3, b3, N3, s4, e4, b4>(A, Bb, D1, tid);
    pool64<N3, b3, p0>(D2, pr + 3 * POOLP, tid);
    __syncthreads();
    dwt_chunk<s4, e4, b4, N4, s5, e5, b5>(Bb, A, D2, tid);
    pool64<N4, b4, p0>(D1, pr + 2 * POOLP, tid);
    __syncthreads();
    pool64<N5, b5, p0>(A,  pr + 0 * POOLP, tid);
    pool64<N5, b5, p0>(D2, pr + 1 * POOLP, tid);
}

__global__ __launch_bounds__(NTHR, 4) void dwt_pool_kernel(const float* __restrict__ x,
                                                           __fp16* __restrict__ pooled,
                                                           const float* __restrict__ lw,
                                                           const float* __restrict__ fw,
                                                           h2* __restrict__ lwh,   // null -> skip pack
                                                           h2* __restrict__ fwh) {
    __shared__ __align__(16) float A[4192];
    __shared__ __align__(16) float Bb[2144];
    __shared__ __align__(16) float D1[2144];
    __shared__ __align__(16) float D2[1088];
    const int tid = threadIdx.x;

    // folded weight packing: first 800 blocks convert 256 f32 pairs each
    // (independent of the dwt below; mlp launches after this kernel completes)
    if (lwh != nullptr && blockIdx.x < PACK_BLOCKS && tid < 256) {
        const int i = blockIdx.x * 256 + tid;
        if (i < LW_PAIRS) {
            const float2 v = reinterpret_cast<const float2*>(lw)[i];
            lwh[i] = __builtin_amdgcn_cvt_pkrtz(v.x, v.y);
        } else {
            const float2 v = reinterpret_cast<const float2*>(fw)[i - LW_PAIRS];
            fwh[i - LW_PAIRS] = __builtin_amdgcn_cvt_pkrtz(v.x, v.y);
        }
    }

    const int row = blockIdx.x >> 1;
    const float* __restrict__ xr = x + (size_t)row * SIGLEN;
    __fp16* __restrict__ pr = pooled + (size_t)row * COMB;
    if (blockIdx.x & 1) dwt_body<1>(xr, pr, A, Bb, D1, D2, tid);
    else                dwt_body<0>(xr, pr, A, Bb, D1, D2, tid);
}

// ---------------- MLP (r18: f16 pooled input, pre-packed f16 weights) ----------------

__global__ __launch_bounds__(1024, 4) void mlp_kernel(const __fp16* __restrict__ pooled,
                                                      const h2* __restrict__ lwh,
                                                      const float* __restrict__ lb,
                                                      const h2* __restrict__ fwh,
                                                      const float* __restrict__ fb,
                                                      float* __restrict__ out) {
    __shared__ h2 sph[8][COMB / 2];
    __shared__ h2 sch[8][COMB / 2];
    const int tid = threadIdx.x;
    const int r0 = blockIdx.x * 8;

    const h2* __restrict__ srcp = reinterpret_cast<const h2*>(pooled + (size_t)r0 * COMB);
    for (int i = tid; i < 8 * (COMB / 2); i += 1024) {
        (&sph[0][0])[i] = srcp[i];
    }
    __syncthreads();

    for (int idx = tid; idx < COMB * 2; idx += 1024) {
        const int c = idx >> 1, rh = (idx & 1) * 4;
        const h2* __restrict__ w = lwh + (size_t)c * 64;
        const int lb2 = (c >> 7) * 64;
        const float bias = lb[c];
        float acc[4] = {bias, bias, bias, bias};
        for (int t2 = 0; t2 < 64; t2 += 4) {
            const float4 wraw = *reinterpret_cast<const float4*>(w + t2);
            const h2 w0 = __builtin_bit_cast(h2, wraw.x);
            const h2 w1 = __builtin_bit_cast(h2, wraw.y);
            const h2 w2 = __builtin_bit_cast(h2, wraw.z);
            const h2 w3 = __builtin_bit_cast(h2, wraw.w);
#pragma unroll
            for (int r = 0; r < 4; ++r) {
                const float4 praw = *reinterpret_cast<const float4*>(&sph[rh + r][lb2 + t2]);
                acc[r] = __builtin_amdgcn_fdot2(__builtin_bit_cast(h2, praw.x), w0, acc[r], false);
                acc[r] = __builtin_amdgcn_fdot2(__builtin_bit_cast(h2, praw.y), w1, acc[r], false);
                acc[r] = __builtin_amdgcn_fdot2(__builtin_bit_cast(h2, praw.z), w2, acc[r], false);
                acc[r] = __builtin_amdgcn_fdot2(__builtin_bit_cast(h2, praw.w), w3, acc[r], false);
            }
        }
        __fp16* __restrict__ schf = reinterpret_cast<__fp16*>(&sch[0][0]);
#pragma unroll
        for (int r = 0; r < 4; ++r) schf[(rh + r) * COMB + c] = (__fp16)fmaxf(acc[r], 0.f);
    }
    __syncthreads();

    {
        const int c = tid >> 1, rh = (tid & 1) * 4;
        const h2* __restrict__ w = fwh + (size_t)c * (COMB / 2);
        const float bias = fb[c];
        float acc[4] = {bias, bias, bias, bias};
        for (int t2 = 0; t2 < COMB / 2; t2 += 4) {
            const float4 wraw = *reinterpret_cast<const float4*>(w + t2);
            const h2 w0 = __builtin_bit_cast(h2, wraw.x);
            const h2 w1 = __builtin_bit_cast(h2, wraw.y);
            const h2 w2 = __builtin_bit_cast(h2, wraw.z);
            const h2 w3 = __builtin_bit_cast(h2, wraw.w);
#pragma unroll
            for (int r = 0; r < 4; ++r) {
                const float4 craw = *reinterpret_cast<const float4*>(&sch[rh + r][t2]);
                acc[r] = __builtin_amdgcn_fdot2(__builtin_bit_cast(h2, craw.x), w0, acc[r], false);
                acc[r] = __builtin_amdgcn_fdot2(__builtin_bit_cast(h2, craw.y), w1, acc[r], false);
                acc[r] = __builtin_amdgcn_fdot2(__builtin_bit_cast(h2, craw.z), w2, acc[r], false);
                acc[r] = __builtin_amdgcn_fdot2(__builtin_bit_cast(h2, craw.w), w3, acc[r], false);
            }
        }
#pragma unroll
        for (int r = 0; r < 4; ++r) {
            out[(size_t)(r0 + rh + r) * OUTD + c] = fmaxf(acc[r], 0.f);
        }
    }
}

// Fallback mlp: in-kernel weight cvt (used if d_ws lacks packed-weight space)
__global__ __launch_bounds__(512) void mlp_kernel_fb(const __fp16* __restrict__ pooled,
                                                     const float* __restrict__ lw,
                                                     const float* __restrict__ lb,
                                                     const float* __restrict__ fw,
                                                     const float* __restrict__ fb,
                                                     float* __restrict__ out) {
    __shared__ h2 sph[8][COMB / 2];
    __shared__ h2 sch[8][COMB / 2];
    const int tid = threadIdx.x;
    const int r0 = blockIdx.x * 8;
    const h2* __restrict__ srcp = reinterpret_cast<const h2*>(pooled + (size_t)r0 * COMB);
    for (int i = tid; i < 8 * (COMB / 2); i += 512) {
        (&sph[0][0])[i] = srcp[i];
    }
    __syncthreads();
    for (int c = tid; c < COMB; c += 512) {
        const float* __restrict__ w = lw + (size_t)c * POOLP;
        const int lb2 = (c >> 7) * (POOLP / 2);
        const float bias = lb[c];
        float acc[8];
#pragma unroll
        for (int r = 0; r < 8; ++r) acc[r] = bias;
        for (int t2 = 0; t2 < POOLP / 2; t2 += 4) {
            const float4 wa = *reinterpret_cast<const float4*>(w + t2 * 2);
            const float4 wb = *reinterpret_cast<const float4*>(w + t2 * 2 + 4);
            const h2 w0 = __builtin_amdgcn_cvt_pkrtz(wa.x, wa.y);
            const h2 w1 = __builtin_amdgcn_cvt_pkrtz(wa.z, wa.w);
            const h2 w2 = __builtin_amdgcn_cvt_pkrtz(wb.x, wb.y);
            const h2 w3 = __builtin_amdgcn_cvt_pkrtz(wb.z, wb.w);
#pragma unroll
            for (int r = 0; r < 8; ++r) {
                const float4 raw = *reinterpret_cast<const float4*>(&sph[r][lb2 + t2]);
                acc[r] = __builtin_amdgcn_fdot2(__builtin_bit_cast(h2, raw.x), w0, acc[r], false);
                acc[r] = __builtin_amdgcn_fdot2(__builtin_bit_cast(h2, raw.y), w1, acc[r], false);
                acc[r] = __builtin_amdgcn_fdot2(__builtin_bit_cast(h2, raw.z), w2, acc[r], false);
                acc[r] = __builtin_amdgcn_fdot2(__builtin_bit_cast(h2, raw.w), w3, acc[r], false);
            }
        }
        __fp16* __restrict__ schf = reinterpret_cast<__fp16*>(&sch[0][0]);
#pragma unroll
        for (int r = 0; r < 8; ++r) schf[r * COMB + c] = (__fp16)fmaxf(acc[r], 0.f);
    }
    __syncthreads();
    {
        const int j = tid;
        const float* __restrict__ w = fw + (size_t)j * COMB;
        const float bias = fb[j];
        float acc[8];
#pragma unroll
        for (int r = 0; r < 8; ++r) acc[r] = bias;
        for (int t2 = 0; t2 < COMB / 2; t2 += 4) {
            const float4 wa = *reinterpret_cast<const float4*>(w + t2 * 2);
            const float4 wb = *reinterpret_cast<const float4*>(w + t2 * 2 + 4);
            const h2 w0 = __builtin_amdgcn_cvt_pkrtz(wa.x, wa.y);
            const h2 w1 = __builtin_amdgcn_cvt_pkrtz(wa.z, wa.w);
            const h2 w2 = __builtin_amdgcn_cvt_pkrtz(wb.x, wb.y);
            const h2 w3 = __builtin_amdgcn_cvt_pkrtz(wb.z, wb.w);
#pragma unroll
            for (int r = 0; r < 8; ++r) {
                const float4 raw = *reinterpret_cast<const float4*>(&sch[r][t2]);
                acc[r] = __builtin_amdgcn_fdot2(__builtin_bit_cast(h2, raw.x), w0, acc[r], false);
                acc[r] = __builtin_amdgcn_fdot2(__builtin_bit_cast(h2, raw.y), w1, acc[r], false);
                acc[r] = __builtin_amdgcn_fdot2(__builtin_bit_cast(h2, raw.z), w2, acc[r], false);
                acc[r] = __builtin_amdgcn_fdot2(__builtin_bit_cast(h2, raw.w), w3, acc[r], false);
            }
        }
#pragma unroll
        for (int r = 0; r < 8; ++r) {
            out[(size_t)(r0 + r) * OUTD + j] = fmaxf(acc[r], 0.f);
        }
    }
}

extern "C" void kernel_launch(void* const* d_in, const int* in_sizes, int n_in,
                              void* d_out, int out_size, void* d_ws, size_t ws_size,
                              hipStream_t stream) {
    const float* x  = (const float*)d_in[0];
    const float* lw = (const float*)d_in[1];
    const float* lb = (const float*)d_in[2];
    const float* fw = (const float*)d_in[3];
    const float* fb = (const float*)d_in[4];
    float* out = (float*)d_out;

    char* base = (char*)d_ws;
    const size_t POOLED_B = (size_t)BATCH * COMB * 2;            // f16, 2,621,440
    const size_t LWH_B    = (size_t)LW_PAIRS * 4;                // 163,840
    const size_t FWH_B    = (size_t)FW_PAIRS * 4;                // 655,360

    __fp16* pooled = (__fp16*)base;
    h2* lwh = (h2*)(base + POOLED_B);
    h2* fwh = (h2*)(base + POOLED_B + LWH_B);

    const bool packed = (ws_size >= POOLED_B + LWH_B + FWH_B);

    dwt_pool_kernel<<<BATCH * 2, NTHR, 0, stream>>>(x, pooled, lw, fw,
                                                    packed ? lwh : nullptr,
                                                    packed ? fwh : nullptr);

    if (packed) {
        mlp_kernel<<<BATCH / 8, 1024, 0, stream>>>(pooled, lwh, lb, fwh, fb, out);
    } else {
        mlp_kernel_fb<<<BATCH / 8, 512, 0, stream>>>(pooled, lw, lb, fw, fb, out);
    }
}